// Round 6
// baseline (300.497 us; speedup 1.0000x reference)
//
#include <hip/hip_runtime.h>
#include <hip/hip_cooperative_groups.h>
#include <cmath>

namespace cg = cooperative_groups;

#define NB 4
#define NT 20
#define NC 128
#define ND 64
#define TD 1280   // T*D

typedef short short8 __attribute__((ext_vector_type(8)));
typedef float f32x4 __attribute__((ext_vector_type(4)));

static __device__ __forceinline__ unsigned short f2bf(float f) {
  union { float f; unsigned int u; } v; v.f = f;
  unsigned int r = v.u + 0x7FFFu + ((v.u >> 16) & 1u);
  return (unsigned short)(r >> 16);
}

static __device__ __forceinline__ void conv16(const float* __restrict__ s,
                                              unsigned short* __restrict__ d) {
#pragma unroll
  for (int q = 0; q < 2; q++) {
    float4 f0 = *(const float4*)(s + q * 8);
    float4 f1 = *(const float4*)(s + q * 8 + 4);
    uint4 o;
    o.x = (unsigned)f2bf(f0.x) | ((unsigned)f2bf(f0.y) << 16);
    o.y = (unsigned)f2bf(f0.z) | ((unsigned)f2bf(f0.w) << 16);
    o.z = (unsigned)f2bf(f1.x) | ((unsigned)f2bf(f1.y) << 16);
    o.w = (unsigned)f2bf(f1.z) | ((unsigned)f2bf(f1.w) << 16);
    *(uint4*)(d + q * 8) = o;
  }
}

// ===========================================================================
// Cooperative mega-kernel: all 5 phases, 4 grid syncs, 1 dispatch.
// Grid MUST be 512 x 256 (2 blocks/CU co-resident; LDS 64 KB/block).
// ===========================================================================
__global__ __launch_bounds__(256) void k_mega(
    const float* __restrict__ h, const float* __restrict__ W1,
    const float* __restrict__ b1, const float* __restrict__ W2,
    const float* __restrict__ b2, const float* __restrict__ W3,
    const float* __restrict__ b3, const float* __restrict__ W4,
    const float* __restrict__ b4, const float* __restrict__ A_a,
    const float* __restrict__ A_m, const float* __restrict__ W_add,
    const float* __restrict__ b_add, const float* __restrict__ W_mod,
    const float* __restrict__ b_mod, const float* __restrict__ beta1p,
    const float* __restrict__ beta2p, const float* __restrict__ beta3p,
    float* __restrict__ out,
    unsigned short* __restrict__ hbf, unsigned short* __restrict__ W1bf,
    unsigned short* __restrict__ W2bf, unsigned short* __restrict__ W3bf,
    unsigned short* __restrict__ A_mTbf, unsigned short* __restrict__ W_addbf,
    unsigned short* __restrict__ W_modbf, unsigned short* __restrict__ hbfT,
    float* __restrict__ part, float* __restrict__ fuv,
    unsigned short* __restrict__ wTbf) {
  cg::grid_group grid = cg::this_grid();
  __shared__ char smem[65536];
  const int blk = blockIdx.x;
  const int tid = threadIdx.x;
  const int lane = tid & 63;
  const int w = tid >> 6;
  const int lr = lane & 15, lhi = lane >> 4;

  // ---------------- P0: conversions (same mapping as standalone k_conv) ----
  if (blk < 160) {                     // h -> hbf (h_flat [b*C+c][t*D+d])
    int bt = blk >> 1;
    int j = ((blk & 1) << 12) + tid * 16;
    int b = bt / 20;
    int c = j >> 6, d0 = j & 63;
    int t5 = bt - b * 20;
    conv16(h + (size_t)bt * 8192 + j,
           hbf + ((size_t)(b * NC + c)) * TD + t5 * 64 + d0);
  } else if (blk < 240) {              // W1
    size_t i = (size_t)(blk - 160) * 4096 + tid * 16;
    conv16(W1 + i, W1bf + i);
  } else if (blk < 248) {              // W2
    size_t i = (size_t)(blk - 240) * 4096 + tid * 16;
    conv16(W2 + i, W2bf + i);
  } else if (blk < 252) {              // W3
    size_t i = (size_t)(blk - 248) * 4096 + tid * 16;
    conv16(W3 + i, W3bf + i);
  } else if (blk < 256) {              // A_m transpose
    size_t base = (size_t)(blk - 252) * 4096 + tid * 16;
    unsigned short tmp[16];
#pragma unroll
    for (int i2 = 0; i2 < 16; i2++) {
      size_t idx = base + i2;
      int v = (int)(idx >> 7), u = (int)(idx & 127);
      tmp[i2] = f2bf(A_m[(size_t)u * 128 + v]);
    }
    *(uint4*)(A_mTbf + base) = *(uint4*)tmp;
    *(uint4*)(A_mTbf + base + 8) = *(uint4*)(tmp + 8);
  } else if (blk < 258) {              // W_add / W_mod
    size_t i = (size_t)tid * 16;
    if (blk == 256) conv16(W_add + i, W_addbf + i);
    else            conv16(W_mod + i, W_modbf + i);
  } else if (blk < 338) {              // hbfT: per-(b,t) [d][u]
    float (*hsl)[65] = (float (*)[65])smem;   // 33 KB < 64 KB
    int bt = blk - 258;
    const float* hb = h + (size_t)bt * 8192;
    for (int i = tid; i < 8192; i += 256) hsl[i >> 6][i & 63] = hb[i];
    __syncthreads();
    unsigned short* ob = hbfT + (size_t)bt * 8192;
    for (int i = tid; i < 8192; i += 256) {
      int d = i >> 7, u = i & 127;
      ob[i] = f2bf(hsl[u][d]);
    }
  }
  grid.sync();

  // ---------------- P1: fuv GEMM, split-K=8, all 512 blocks ---------------
  // block = (mt 16, nt 4, ks 8); wave = M16 x N32 x K160 (mh=w&1, nh=w>>1)
  {
    int mt = blk & 15, nt = (blk >> 4) & 3, ks = blk >> 6;
    int mh = w & 1, nh = w >> 1;
    int kc0 = ks * 160;
    int arow = mt * 32 + mh * 16 + lr;
    const unsigned short* ap = hbf + (size_t)arow * TD + kc0 + lhi * 8;
    const unsigned short* bp[2];
#pragma unroll
    for (int nf = 0; nf < 2; nf++) {
      int n = nt * 64 + nh * 32 + nf * 16 + lr;
      bp[nf] = W1bf + (size_t)(n & 127) * (2 * TD) + (n >> 7) * TD + kc0 + lhi * 8;
    }
    f32x4 acc[2];
    acc[0] = (f32x4){0.f, 0.f, 0.f, 0.f};
    acc[1] = (f32x4){0.f, 0.f, 0.f, 0.f};
#pragma unroll
    for (int kb = 0; kb < 160; kb += 32) {
      short8 a = *(const short8*)(ap + kb);
#pragma unroll
      for (int nf = 0; nf < 2; nf++) {
        short8 bv = *(const short8*)(bp[nf] + kb);
        acc[nf] = __builtin_amdgcn_mfma_f32_16x16x32_bf16(a, bv, acc[nf], 0, 0, 0);
      }
    }
    float* pout = part + (size_t)ks * 131072;
    int m0 = mt * 32 + mh * 16 + lhi * 4;
#pragma unroll
    for (int nf = 0; nf < 2; nf++)
#pragma unroll
      for (int r = 0; r < 4; r++)
        pout[(size_t)(m0 + r) * 256 + nt * 64 + nh * 32 + nf * 16 + lr] = acc[nf][r];
  }
  grid.sync();

  // ---------------- P2: split-K reduce (exactly 1 f32 per thread) ---------
  {
    int gid = blk * 256 + tid;
    float s = part[gid];
#pragma unroll
    for (int p = 1; p < 8; p++) s += part[(size_t)p * 131072 + gid];
    fuv[gid] = s;
  }
  grid.sync();

  // ---------------- P3: pairwise MLP (R5 k_pair body) ---------------------
  {
    int b = blk >> 7;
    int u = blk & 127;
    char* x1raw = smem;                 // 32 KB
    char* ycb = smem + 32768 + w * 8192;
    const float* fub = fuv + ((size_t)(b * NC + u)) * 256;
    {
      int v = tid >> 1;
      int kh2 = (tid & 1) << 6;
      const float* fvrow = fuv + ((size_t)(b * NC + v)) * 256 + 128 + kh2;
      const float* fur = fub + kh2;
      const float* b1r = b1 + kh2;
      int swv = (v & 7) << 4;
      int rowbase = v * 256 + kh2 * 2;
      for (int kc = 0; kc < 64; kc += 8) {
        float e[8];
#pragma unroll
        for (int i2 = 0; i2 < 8; i2++) {
          float val = fur[kc + i2] + fvrow[kc + i2] + b1r[kc + i2];
          e[i2] = val > 0.f ? val : 0.f;
        }
        unsigned int pw[4];
#pragma unroll
        for (int i2 = 0; i2 < 4; i2++)
          pw[i2] = (unsigned int)f2bf(e[2 * i2]) |
                   ((unsigned int)f2bf(e[2 * i2 + 1]) << 16);
        *(uint4*)(x1raw + ((rowbase + kc * 2) ^ swv)) =
            make_uint4(pw[0], pw[1], pw[2], pw[3]);
      }
    }
    __syncthreads();

    int v0w = w * 32;
    int sw = (lr & 7) << 4;

    f32x4 zacc[2][4];
#pragma unroll
    for (int q = 0; q < 2; q++)
#pragma unroll
      for (int n = 0; n < 4; n++) zacc[q][n] = (f32x4){0.f, 0.f, 0.f, 0.f};

    for (int mc = 0; mc < 256; mc += 64) {
      f32x4 yac[4][2];
#pragma unroll
      for (int mt = 0; mt < 4; mt++) {
        yac[mt][0] = (f32x4){0.f, 0.f, 0.f, 0.f};
        yac[mt][1] = (f32x4){0.f, 0.f, 0.f, 0.f};
      }
#pragma unroll
      for (int ks = 0; ks < 4; ks++) {
        int kb = ks * 32 + lhi * 8;
        int r0 = (v0w + lr) * 256 + kb * 2;
        short8 x0 = *(const short8*)(x1raw + (r0 ^ sw));
        short8 x1v = *(const short8*)(x1raw + ((r0 + 16 * 256) ^ sw));
#pragma unroll
        for (int mt = 0; mt < 4; mt++) {
          const unsigned short* wp = W2bf + (size_t)(mc + mt * 16 + lr) * 128 + kb;
          short8 wv = *(const short8*)wp;
          yac[mt][0] = __builtin_amdgcn_mfma_f32_16x16x32_bf16(wv, x0, yac[mt][0], 0, 0, 0);
          yac[mt][1] = __builtin_amdgcn_mfma_f32_16x16x32_bf16(wv, x1v, yac[mt][1], 0, 0, 0);
        }
      }
#pragma unroll
      for (int mt = 0; mt < 4; mt++) {
        float4 b2v = *(const float4*)(b2 + mc + mt * 16 + lhi * 4);
#pragma unroll
        for (int vg = 0; vg < 2; vg++) {
          int v = vg * 16 + lr;
          float e0 = yac[mt][vg][0] + b2v.x; e0 = e0 > 0.f ? e0 : 0.f;
          float e1 = yac[mt][vg][1] + b2v.y; e1 = e1 > 0.f ? e1 : 0.f;
          float e2 = yac[mt][vg][2] + b2v.z; e2 = e2 > 0.f ? e2 : 0.f;
          float e3 = yac[mt][vg][3] + b2v.w; e3 = e3 > 0.f ? e3 : 0.f;
          uint2 pw;
          pw.x = (unsigned)f2bf(e0) | ((unsigned)f2bf(e1) << 16);
          pw.y = (unsigned)f2bf(e2) | ((unsigned)f2bf(e3) << 16);
          int byte = (v * 128 + (mt * 16 + lhi * 4) * 2) ^ ((lr & 7) << 4);
          *(uint2*)(ycb + byte) = pw;
        }
      }
#pragma unroll
      for (int ks = 0; ks < 2; ks++) {
        int kb = ks * 32 + lhi * 8;
        short8 ya0 = *(const short8*)(ycb + ((lr * 128 + kb * 2) ^ sw));
        short8 ya1 = *(const short8*)(ycb + (((16 + lr) * 128 + kb * 2) ^ sw));
#pragma unroll
        for (int n = 0; n < 4; n++) {
          const unsigned short* wp = W3bf + (size_t)(16 * n + lr) * 256 + mc + kb;
          short8 w3v = *(const short8*)wp;
          zacc[0][n] = __builtin_amdgcn_mfma_f32_16x16x32_bf16(ya0, w3v, zacc[0][n], 0, 0, 0);
          zacc[1][n] = __builtin_amdgcn_mfma_f32_16x16x32_bf16(ya1, w3v, zacc[1][n], 0, 0, 0);
        }
      }
    }

    float sp[2][4];
#pragma unroll
    for (int q = 0; q < 2; q++)
#pragma unroll
      for (int r = 0; r < 4; r++) sp[q][r] = 0.f;
#pragma unroll
    for (int n = 0; n < 4; n++) {
      int j = 16 * n + lr;
      float b3v = b3[j], w4v = W4[j];
#pragma unroll
      for (int q = 0; q < 2; q++)
#pragma unroll
        for (int r = 0; r < 4; r++) {
          float z = zacc[q][n][r] + b3v;
          z = z > 0.f ? z : 0.f;
          sp[q][r] += w4v * z;
        }
    }
#pragma unroll
    for (int mask = 1; mask <= 8; mask <<= 1)
#pragma unroll
      for (int q = 0; q < 2; q++)
#pragma unroll
        for (int r = 0; r < 4; r++)
          sp[q][r] += __shfl_xor(sp[q][r], mask, 64);
    float bb4 = b4[0];
    if (lr == 0) {
#pragma unroll
      for (int q = 0; q < 2; q++)
#pragma unroll
        for (int r = 0; r < 4; r++) {
          int v = v0w + 16 * q + lhi * 4 + r;
          float s = 1.f / (1.f + expf(-(sp[q][r] + bb4)));
          wTbf[((size_t)(b * NC + v)) * NC + u] = f2bf(s * A_a[u * NC + v]);
        }
    }
  }
  grid.sync();

  // ---------------- P4: out (R5 k_out_mfma body, 640 wave-items) ----------
  {
    int item = w * 512 + blk;
    if (item < 640) {
      int bt = item >> 3;
      int v0 = (item & 7) << 4;
      int b = bt / 20;
      char* apre_l = smem + w * 4096;        // per-wave 2 KB
      char* mpre_l = smem + w * 4096 + 2048; // per-wave 2 KB

      f32x4 aacc[4], macc[4];
#pragma unroll
      for (int nf = 0; nf < 4; nf++) {
        aacc[nf] = (f32x4){0.f, 0.f, 0.f, 0.f};
        macc[nf] = (f32x4){0.f, 0.f, 0.f, 0.f};
      }
      const unsigned short* wrow = wTbf + ((size_t)(b * NC + v0 + lr)) * NC + lhi * 8;
      const unsigned short* arow = A_mTbf + (size_t)(v0 + lr) * NC + lhi * 8;
      const unsigned short* hTrow = hbfT + (size_t)bt * 8192 + lhi * 8;
#pragma unroll
      for (int kb = 0; kb < 128; kb += 32) {
        short8 aw = *(const short8*)(wrow + kb);
        short8 am = *(const short8*)(arow + kb);
#pragma unroll
        for (int nf = 0; nf < 4; nf++) {
          short8 bv = *(const short8*)(hTrow + (size_t)(nf * 16 + lr) * NC + kb);
          aacc[nf] = __builtin_amdgcn_mfma_f32_16x16x32_bf16(aw, bv, aacc[nf], 0, 0, 0);
          macc[nf] = __builtin_amdgcn_mfma_f32_16x16x32_bf16(am, bv, macc[nf], 0, 0, 0);
        }
      }

      float hval[4][4];
      const float* hbase = h + (size_t)bt * 8192;
#pragma unroll
      for (int nf = 0; nf < 4; nf++) {
        int d = nf * 16 + lr;
#pragma unroll
        for (int r = 0; r < 4; r++) {
          int vl = lhi * 4 + r;
          float hv = hbase[(size_t)(v0 + vl) * 64 + d];
          hval[nf][r] = hv;
          int byte = (vl * 128 + d * 2) ^ ((vl & 7) << 4);
          *(unsigned short*)(apre_l + byte) = f2bf(aacc[nf][r]);
          *(unsigned short*)(mpre_l + byte) = f2bf(macc[nf][r] * hv);
        }
      }
      // single wave: LDS RAW handled by lgkmcnt, no barrier

      f32x4 oa[4], om[4];
#pragma unroll
      for (int nf = 0; nf < 4; nf++) {
        oa[nf] = (f32x4){0.f, 0.f, 0.f, 0.f};
        om[nf] = (f32x4){0.f, 0.f, 0.f, 0.f};
      }
      int sw = (lr & 7) << 4;
#pragma unroll
      for (int kb = 0; kb < 64; kb += 32) {
        int off0 = lr * 128 + kb * 2 + lhi * 16;
        short8 pa = *(const short8*)(apre_l + (off0 ^ sw));
        short8 pm = *(const short8*)(mpre_l + (off0 ^ sw));
#pragma unroll
        for (int nf = 0; nf < 4; nf++) {
          const unsigned short* wa = W_addbf + (size_t)(nf * 16 + lr) * 64 + kb + lhi * 8;
          const unsigned short* wm = W_modbf + (size_t)(nf * 16 + lr) * 64 + kb + lhi * 8;
          short8 wav = *(const short8*)wa;
          short8 wmv = *(const short8*)wm;
          oa[nf] = __builtin_amdgcn_mfma_f32_16x16x32_bf16(pa, wav, oa[nf], 0, 0, 0);
          om[nf] = __builtin_amdgcn_mfma_f32_16x16x32_bf16(pm, wmv, om[nf], 0, 0, 0);
        }
      }

      float bb1 = beta1p[0], bb2 = beta2p[0], bb3 = beta3p[0];
      float* obase = out + (size_t)bt * 8192 + (size_t)v0 * 64;
#pragma unroll
      for (int nf = 0; nf < 4; nf++) {
        int d = nf * 16 + lr;
        float ba = b_add[d], bm = b_mod[d];
#pragma unroll
        for (int r = 0; r < 4; r++) {
          int vl = lhi * 4 + r;
          obase[(size_t)vl * 64 + d] =
              bb1 * hval[nf][r] + bb2 * (oa[nf][r] + ba) + bb3 * (om[nf][r] + bm);
        }
      }
    }
  }
}

// ===========================================================================
// Fallback path (R5 5-kernel pipeline, verbatim) in case cooperative launch
// is rejected by the runtime/capture.
// ===========================================================================
__global__ __launch_bounds__(256) void k_conv(
    const float* __restrict__ h, const float* __restrict__ W1,
    const float* __restrict__ W2, const float* __restrict__ W3,
    const float* __restrict__ A_m, const float* __restrict__ W_add,
    const float* __restrict__ W_mod,
    unsigned short* __restrict__ hbf, unsigned short* __restrict__ W1bf,
    unsigned short* __restrict__ W2bf, unsigned short* __restrict__ W3bf,
    unsigned short* __restrict__ A_mTbf, unsigned short* __restrict__ W_addbf,
    unsigned short* __restrict__ W_modbf, unsigned short* __restrict__ hbfT) {
  __shared__ float hsl[128][65];
  int blk = blockIdx.x, tid = threadIdx.x;
  if (blk < 160) {
    int bt = blk >> 1;
    int j = ((blk & 1) << 12) + tid * 16;
    int b = bt / 20;
    int c = j >> 6, d0 = j & 63;
    int t5 = bt - b * 20;
    conv16(h + (size_t)bt * 8192 + j,
           hbf + ((size_t)(b * NC + c)) * TD + t5 * 64 + d0);
  } else if (blk < 240) {
    size_t i = (size_t)(blk - 160) * 4096 + tid * 16;
    conv16(W1 + i, W1bf + i);
  } else if (blk < 248) {
    size_t i = (size_t)(blk - 240) * 4096 + tid * 16;
    conv16(W2 + i, W2bf + i);
  } else if (blk < 252) {
    size_t i = (size_t)(blk - 248) * 4096 + tid * 16;
    conv16(W3 + i, W3bf + i);
  } else if (blk < 256) {
    size_t base = (size_t)(blk - 252) * 4096 + tid * 16;
    unsigned short tmp[16];
#pragma unroll
    for (int i2 = 0; i2 < 16; i2++) {
      size_t idx = base + i2;
      int v = (int)(idx >> 7), u = (int)(idx & 127);
      tmp[i2] = f2bf(A_m[(size_t)u * 128 + v]);
    }
    *(uint4*)(A_mTbf + base) = *(uint4*)tmp;
    *(uint4*)(A_mTbf + base + 8) = *(uint4*)(tmp + 8);
  } else if (blk < 258) {
    size_t i = (size_t)tid * 16;
    if (blk == 256) conv16(W_add + i, W_addbf + i);
    else            conv16(W_mod + i, W_modbf + i);
  } else {
    int bt = blk - 258;
    const float* hb = h + (size_t)bt * 8192;
    for (int i = tid; i < 8192; i += 256) hsl[i >> 6][i & 63] = hb[i];
    __syncthreads();
    unsigned short* ob = hbfT + (size_t)bt * 8192;
    for (int i = tid; i < 8192; i += 256) {
      int d = i >> 7, u = i & 127;
      ob[i] = f2bf(hsl[u][d]);
    }
  }
}

__global__ __launch_bounds__(128) void k_fuv_mfma(
    const unsigned short* __restrict__ hbf,
    const unsigned short* __restrict__ W1bf,
    float* __restrict__ part) {
  int blk = blockIdx.x;
  int mtile = blk & 15;
  int ntile = (blk >> 4) & 3;
  int ks = blk >> 6;
  int t = threadIdx.x;
  int lane = t & 63;
  int w = t >> 6;
  int lr = lane & 15, lhi = lane >> 4;
  int kc0 = ks * 320;
  int row = mtile * 32 + w * 16 + lr;
  const unsigned short* ap = hbf + (size_t)row * TD + kc0 + lhi * 8;
  const unsigned short* bp[4];
#pragma unroll
  for (int nf = 0; nf < 4; nf++) {
    int n = ntile * 64 + nf * 16 + lr;
    bp[nf] = W1bf + (size_t)(n & 127) * (2 * TD) + (n >> 7) * TD + kc0 + lhi * 8;
  }
  f32x4 acc[4];
#pragma unroll
  for (int nf = 0; nf < 4; nf++) acc[nf] = (f32x4){0.f, 0.f, 0.f, 0.f};
#pragma unroll
  for (int kb = 0; kb < 320; kb += 32) {
    short8 a = *(const short8*)(ap + kb);
#pragma unroll
    for (int nf = 0; nf < 4; nf++) {
      short8 bv = *(const short8*)(bp[nf] + kb);
      acc[nf] = __builtin_amdgcn_mfma_f32_16x16x32_bf16(a, bv, acc[nf], 0, 0, 0);
    }
  }
  float* pout = part + (size_t)ks * (512 * 256);
  int m0 = mtile * 32 + w * 16 + lhi * 4;
#pragma unroll
  for (int nf = 0; nf < 4; nf++)
#pragma unroll
    for (int r = 0; r < 4; r++)
      pout[(size_t)(m0 + r) * 256 + ntile * 64 + nf * 16 + lr] = acc[nf][r];
}

__global__ __launch_bounds__(256) void k_fred(
    const float* __restrict__ part, float* __restrict__ fuv) {
  int i = blockIdx.x * 256 + threadIdx.x;
  float4 s = ((const float4*)part)[i];
#pragma unroll
  for (int p = 1; p < 4; p++) {
    float4 v = ((const float4*)part)[i + p * 32768];
    s.x += v.x; s.y += v.y; s.z += v.z; s.w += v.w;
  }
  ((float4*)fuv)[i] = s;
}

__global__ __launch_bounds__(256) void k_pair(
    const float* __restrict__ fuv, const float* __restrict__ b1,
    const unsigned short* __restrict__ W2bf, const float* __restrict__ b2,
    const unsigned short* __restrict__ W3bf, const float* __restrict__ b3,
    const float* __restrict__ W4, const float* __restrict__ b4,
    const float* __restrict__ A_a, unsigned short* __restrict__ wTbf) {
  int blk = blockIdx.x;
  int b = blk >> 7;
  int u = blk & 127;
  __shared__ char x1raw[32768];
  __shared__ char ycraw[4][8192];
  int t = threadIdx.x;
  int lane = t & 63;
  int w = t >> 6;
  const float* fub = fuv + ((size_t)(b * NC + u)) * 256;
  {
    int v = t >> 1;
    int kh2 = (t & 1) << 6;
    const float* fvrow = fuv + ((size_t)(b * NC + v)) * 256 + 128 + kh2;
    const float* fur = fub + kh2;
    const float* b1r = b1 + kh2;
    int sw = (v & 7) << 4;
    int rowbase = v * 256 + kh2 * 2;
    for (int kc = 0; kc < 64; kc += 8) {
      float e[8];
#pragma unroll
      for (int i2 = 0; i2 < 8; i2++) {
        float val = fur[kc + i2] + fvrow[kc + i2] + b1r[kc + i2];
        e[i2] = val > 0.f ? val : 0.f;
      }
      unsigned int pw[4];
#pragma unroll
      for (int i2 = 0; i2 < 4; i2++)
        pw[i2] = (unsigned int)f2bf(e[2 * i2]) |
                 ((unsigned int)f2bf(e[2 * i2 + 1]) << 16);
      *(uint4*)(x1raw + ((rowbase + kc * 2) ^ sw)) =
          make_uint4(pw[0], pw[1], pw[2], pw[3]);
    }
  }
  __syncthreads();
  int v0w = w * 32;
  int lr = lane & 15;
  int lhi = lane >> 4;
  int sw = (lr & 7) << 4;
  char* ycb = ycraw[w];
  f32x4 zacc[2][4];
#pragma unroll
  for (int q = 0; q < 2; q++)
#pragma unroll
    for (int n = 0; n < 4; n++) zacc[q][n] = (f32x4){0.f, 0.f, 0.f, 0.f};
  for (int mc = 0; mc < 256; mc += 64) {
    f32x4 yac[4][2];
#pragma unroll
    for (int mt = 0; mt < 4; mt++) {
      yac[mt][0] = (f32x4){0.f, 0.f, 0.f, 0.f};
      yac[mt][1] = (f32x4){0.f, 0.f, 0.f, 0.f};
    }
#pragma unroll
    for (int ks = 0; ks < 4; ks++) {
      int kb = ks * 32 + lhi * 8;
      int r0 = (v0w + lr) * 256 + kb * 2;
      short8 x0 = *(const short8*)(x1raw + (r0 ^ sw));
      short8 x1v = *(const short8*)(x1raw + ((r0 + 16 * 256) ^ sw));
#pragma unroll
      for (int mt = 0; mt < 4; mt++) {
        const unsigned short* wp = W2bf + (size_t)(mc + mt * 16 + lr) * 128 + kb;
        short8 wv = *(const short8*)wp;
        yac[mt][0] = __builtin_amdgcn_mfma_f32_16x16x32_bf16(wv, x0, yac[mt][0], 0, 0, 0);
        yac[mt][1] = __builtin_amdgcn_mfma_f32_16x16x32_bf16(wv, x1v, yac[mt][1], 0, 0, 0);
      }
    }
#pragma unroll
    for (int mt = 0; mt < 4; mt++) {
      float4 b2v = *(const float4*)(b2 + mc + mt * 16 + lhi * 4);
#pragma unroll
      for (int vg = 0; vg < 2; vg++) {
        int v = vg * 16 + lr;
        float e0 = yac[mt][vg][0] + b2v.x; e0 = e0 > 0.f ? e0 : 0.f;
        float e1 = yac[mt][vg][1] + b2v.y; e1 = e1 > 0.f ? e1 : 0.f;
        float e2 = yac[mt][vg][2] + b2v.z; e2 = e2 > 0.f ? e2 : 0.f;
        float e3 = yac[mt][vg][3] + b2v.w; e3 = e3 > 0.f ? e3 : 0.f;
        uint2 pw;
        pw.x = (unsigned)f2bf(e0) | ((unsigned)f2bf(e1) << 16);
        pw.y = (unsigned)f2bf(e2) | ((unsigned)f2bf(e3) << 16);
        int byte = (v * 128 + (mt * 16 + lhi * 4) * 2) ^ ((lr & 7) << 4);
        *(uint2*)(ycb + byte) = pw;
      }
    }
#pragma unroll
    for (int ks = 0; ks < 2; ks++) {
      int kb = ks * 32 + lhi * 8;
      short8 ya0 = *(const short8*)(ycb + ((lr * 128 + kb * 2) ^ sw));
      short8 ya1 = *(const short8*)(ycb + (((16 + lr) * 128 + kb * 2) ^ sw));
#pragma unroll
      for (int n = 0; n < 4; n++) {
        const unsigned short* wp = W3bf + (size_t)(16 * n + lr) * 256 + mc + kb;
        short8 w3v = *(const short8*)wp;
        zacc[0][n] = __builtin_amdgcn_mfma_f32_16x16x32_bf16(ya0, w3v, zacc[0][n], 0, 0, 0);
        zacc[1][n] = __builtin_amdgcn_mfma_f32_16x16x32_bf16(ya1, w3v, zacc[1][n], 0, 0, 0);
      }
    }
  }
  float sp[2][4];
#pragma unroll
  for (int q = 0; q < 2; q++)
#pragma unroll
    for (int r = 0; r < 4; r++) sp[q][r] = 0.f;
#pragma unroll
  for (int n = 0; n < 4; n++) {
    int j = 16 * n + lr;
    float b3v = b3[j], w4v = W4[j];
#pragma unroll
    for (int q = 0; q < 2; q++)
#pragma unroll
      for (int r = 0; r < 4; r++) {
        float z = zacc[q][n][r] + b3v;
        z = z > 0.f ? z : 0.f;
        sp[q][r] += w4v * z;
      }
  }
#pragma unroll
  for (int mask = 1; mask <= 8; mask <<= 1)
#pragma unroll
    for (int q = 0; q < 2; q++)
#pragma unroll
      for (int r = 0; r < 4; r++)
        sp[q][r] += __shfl_xor(sp[q][r], mask, 64);
  float bb4 = b4[0];
  if (lr == 0) {
#pragma unroll
    for (int q = 0; q < 2; q++)
#pragma unroll
      for (int r = 0; r < 4; r++) {
        int v = v0w + 16 * q + lhi * 4 + r;
        float s = 1.f / (1.f + expf(-(sp[q][r] + bb4)));
        wTbf[((size_t)(b * NC + v)) * NC + u] = f2bf(s * A_a[u * NC + v]);
      }
  }
}

__global__ __launch_bounds__(64) void k_out_mfma(
    const float* __restrict__ h, const unsigned short* __restrict__ wTbf,
    const unsigned short* __restrict__ A_mTbf,
    const unsigned short* __restrict__ hbfT,
    const unsigned short* __restrict__ W_addbf,
    const unsigned short* __restrict__ W_modbf,
    const float* __restrict__ b_add, const float* __restrict__ b_mod,
    const float* __restrict__ beta1p, const float* __restrict__ beta2p,
    const float* __restrict__ beta3p, float* __restrict__ out) {
  int blk = blockIdx.x;
  int bt = blk >> 3;
  int v0 = (blk & 7) << 4;
  int b = bt / 20;
  __shared__ char apre_l[2048];
  __shared__ char mpre_l[2048];
  int lane = threadIdx.x;
  int lr = lane & 15, lhi = lane >> 4;
  f32x4 aacc[4], macc[4];
#pragma unroll
  for (int nf = 0; nf < 4; nf++) {
    aacc[nf] = (f32x4){0.f, 0.f, 0.f, 0.f};
    macc[nf] = (f32x4){0.f, 0.f, 0.f, 0.f};
  }
  const unsigned short* wrow = wTbf + ((size_t)(b * NC + v0 + lr)) * NC + lhi * 8;
  const unsigned short* arow = A_mTbf + (size_t)(v0 + lr) * NC + lhi * 8;
  const unsigned short* hTrow = hbfT + (size_t)bt * 8192 + lhi * 8;
#pragma unroll
  for (int kb = 0; kb < 128; kb += 32) {
    short8 aw = *(const short8*)(wrow + kb);
    short8 am = *(const short8*)(arow + kb);
#pragma unroll
    for (int nf = 0; nf < 4; nf++) {
      short8 bv = *(const short8*)(hTrow + (size_t)(nf * 16 + lr) * NC + kb);
      aacc[nf] = __builtin_amdgcn_mfma_f32_16x16x32_bf16(aw, bv, aacc[nf], 0, 0, 0);
      macc[nf] = __builtin_amdgcn_mfma_f32_16x16x32_bf16(am, bv, macc[nf], 0, 0, 0);
    }
  }
  float hval[4][4];
  const float* hbase = h + (size_t)bt * 8192;
#pragma unroll
  for (int nf = 0; nf < 4; nf++) {
    int d = nf * 16 + lr;
#pragma unroll
    for (int r = 0; r < 4; r++) {
      int vl = lhi * 4 + r;
      float hv = hbase[(size_t)(v0 + vl) * 64 + d];
      hval[nf][r] = hv;
      int byte = (vl * 128 + d * 2) ^ ((vl & 7) << 4);
      *(unsigned short*)(apre_l + byte) = f2bf(aacc[nf][r]);
      *(unsigned short*)(mpre_l + byte) = f2bf(macc[nf][r] * hv);
    }
  }
  f32x4 oa[4], om[4];
#pragma unroll
  for (int nf = 0; nf < 4; nf++) {
    oa[nf] = (f32x4){0.f, 0.f, 0.f, 0.f};
    om[nf] = (f32x4){0.f, 0.f, 0.f, 0.f};
  }
  int sw = (lr & 7) << 4;
#pragma unroll
  for (int kb = 0; kb < 64; kb += 32) {
    int off0 = lr * 128 + kb * 2 + lhi * 16;
    short8 pa = *(const short8*)(apre_l + (off0 ^ sw));
    short8 pm = *(const short8*)(mpre_l + (off0 ^ sw));
#pragma unroll
    for (int nf = 0; nf < 4; nf++) {
      const unsigned short* wa = W_addbf + (size_t)(nf * 16 + lr) * 64 + kb + lhi * 8;
      const unsigned short* wm = W_modbf + (size_t)(nf * 16 + lr) * 64 + kb + lhi * 8;
      short8 wav = *(const short8*)wa;
      short8 wmv = *(const short8*)wm;
      oa[nf] = __builtin_amdgcn_mfma_f32_16x16x32_bf16(pa, wav, oa[nf], 0, 0, 0);
      om[nf] = __builtin_amdgcn_mfma_f32_16x16x32_bf16(pm, wmv, om[nf], 0, 0, 0);
    }
  }
  float bb1 = beta1p[0], bb2 = beta2p[0], bb3 = beta3p[0];
  float* obase = out + (size_t)bt * 8192 + (size_t)v0 * 64;
#pragma unroll
  for (int nf = 0; nf < 4; nf++) {
    int d = nf * 16 + lr;
    float ba = b_add[d], bm = b_mod[d];
#pragma unroll
    for (int r = 0; r < 4; r++) {
      int vl = lhi * 4 + r;
      obase[(size_t)vl * 64 + d] =
          bb1 * hval[nf][r] + bb2 * (oa[nf][r] + ba) + bb3 * (om[nf][r] + bm);
    }
  }
}

// ---------------------------------------------------------------------------
extern "C" void kernel_launch(void* const* d_in, const int* in_sizes, int n_in,
                              void* d_out, int out_size, void* d_ws, size_t ws_size,
                              hipStream_t stream) {
  const float* h     = (const float*)d_in[0];
  const float* W1    = (const float*)d_in[1];
  const float* b1    = (const float*)d_in[2];
  const float* W2    = (const float*)d_in[3];
  const float* b2    = (const float*)d_in[4];
  const float* W3    = (const float*)d_in[5];
  const float* b3    = (const float*)d_in[6];
  const float* W4    = (const float*)d_in[7];
  const float* b4    = (const float*)d_in[8];
  const float* A_a   = (const float*)d_in[9];
  const float* A_m   = (const float*)d_in[10];
  const float* W_add = (const float*)d_in[11];
  const float* b_add = (const float*)d_in[12];
  const float* W_mod = (const float*)d_in[13];
  const float* b_mod = (const float*)d_in[14];
  const float* beta1 = (const float*)d_in[15];
  const float* beta2 = (const float*)d_in[16];
  const float* beta3 = (const float*)d_in[17];
  float* out = (float*)d_out;

  char* ws = (char*)d_ws;
  float* fuv             = (float*)(ws);                         // 512 KB
  unsigned short* wTbf   = (unsigned short*)(ws + 512 * 1024);   // 128 KB
  unsigned short* A_mTbf = (unsigned short*)(ws + 640 * 1024);   // 32 KB
  unsigned short* W_addbf= (unsigned short*)(ws + 672 * 1024);   // 8 KB
  unsigned short* W_modbf= (unsigned short*)(ws + 680 * 1024);   // 8 KB
  unsigned short* W2bf   = (unsigned short*)(ws + 688 * 1024);   // 64 KB
  unsigned short* W3bf   = (unsigned short*)(ws + 752 * 1024);   // 32 KB
  unsigned short* W1bf   = (unsigned short*)(ws + 784 * 1024);   // 640 KB
  unsigned short* hbf    = (unsigned short*)(ws + 1424 * 1024);  // 1280 KB
  unsigned short* hbfT   = (unsigned short*)(ws + 2704 * 1024);  // 1280 KB
  float* part            = (float*)(ws + 3984 * 1024);           // 4096 KB (8 splits)

  void* args[] = {
      (void*)&h, (void*)&W1, (void*)&b1, (void*)&W2, (void*)&b2,
      (void*)&W3, (void*)&b3, (void*)&W4, (void*)&b4, (void*)&A_a,
      (void*)&A_m, (void*)&W_add, (void*)&b_add, (void*)&W_mod, (void*)&b_mod,
      (void*)&beta1, (void*)&beta2, (void*)&beta3, (void*)&out,
      (void*)&hbf, (void*)&W1bf, (void*)&W2bf, (void*)&W3bf, (void*)&A_mTbf,
      (void*)&W_addbf, (void*)&W_modbf, (void*)&hbfT, (void*)&part,
      (void*)&fuv, (void*)&wTbf};

  hipError_t e = hipLaunchCooperativeKernel((const void*)k_mega, dim3(512),
                                            dim3(256), args, 0, stream);
  if (e != hipSuccess) {
    (void)hipGetLastError();   // clear sticky error, use fallback pipeline
    k_conv<<<338, 256, 0, stream>>>(h, W1, W2, W3, A_m, W_add, W_mod,
                                    hbf, W1bf, W2bf, W3bf, A_mTbf, W_addbf,
                                    W_modbf, hbfT);
    k_fuv_mfma<<<256, 128, 0, stream>>>(hbf, W1bf, part);
    k_fred<<<128, 256, 0, stream>>>(part, fuv);
    k_pair<<<512, 256, 0, stream>>>(fuv, b1, W2bf, b2, W3bf, b3, W4, b4, A_a, wTbf);
    k_out_mfma<<<640, 64, 0, stream>>>(h, wTbf, A_mTbf, hbfT, W_addbf, W_modbf,
                                       b_add, b_mod, beta1, beta2, beta3, out);
  }
}

// Round 7
// 69.720 us; speedup vs baseline: 4.3100x; 4.3100x over previous
//
#include <hip/hip_runtime.h>
#include <cmath>

#define NB 4
#define NT 20
#define NC 128
#define ND 64
#define TD 1280   // T*D

typedef short short8 __attribute__((ext_vector_type(8)));
typedef float f32x4 __attribute__((ext_vector_type(4)));

static __device__ __forceinline__ unsigned short f2bf(float f) {
  union { float f; unsigned int u; } v; v.f = f;
  unsigned int r = v.u + 0x7FFFu + ((v.u >> 16) & 1u);
  return (unsigned short)(r >> 16);
}

static __device__ __forceinline__ void conv16(const float* __restrict__ s,
                                              unsigned short* __restrict__ d) {
#pragma unroll
  for (int q = 0; q < 2; q++) {
    float4 f0 = *(const float4*)(s + q * 8);
    float4 f1 = *(const float4*)(s + q * 8 + 4);
    uint4 o;
    o.x = (unsigned)f2bf(f0.x) | ((unsigned)f2bf(f0.y) << 16);
    o.y = (unsigned)f2bf(f0.z) | ((unsigned)f2bf(f0.w) << 16);
    o.z = (unsigned)f2bf(f1.x) | ((unsigned)f2bf(f1.y) << 16);
    o.w = (unsigned)f2bf(f1.z) | ((unsigned)f2bf(f1.w) << 16);
    *(uint4*)(d + q * 8) = o;
  }
}

// Pack 8 f32 -> 8 bf16 (RNE) via native v_cvt_pk_bf16_f32.
static __device__ __forceinline__ short8 cvt8(float4 x, float4 y) {
  union { unsigned int u[4]; short8 s; } r;
  asm("v_cvt_pk_bf16_f32 %0, %1, %2" : "=v"(r.u[0]) : "v"(x.x), "v"(x.y));
  asm("v_cvt_pk_bf16_f32 %0, %1, %2" : "=v"(r.u[1]) : "v"(x.z), "v"(x.w));
  asm("v_cvt_pk_bf16_f32 %0, %1, %2" : "=v"(r.u[2]) : "v"(y.x), "v"(y.y));
  asm("v_cvt_pk_bf16_f32 %0, %1, %2" : "=v"(r.u[3]) : "v"(y.z), "v"(y.w));
  return r.s;
}

// ---------------------------------------------------------------------------
// k_front: ONE dispatch, two independent roles.
//  blk <128  : fuv GEMM  (M=512, N=256, K=1280) reading f32 h/W1 directly,
//              in-register bf16 conversion, NO split-K, writes fuv f32.
//              128 blocks = 16 Mtiles(32) x 8 Ntiles(32); 4 waves: M16 x N16.
//  blk 128.. : bf16 conversions for the later kernels (W2,W3,A_mT,W_add/mod,
//              hbfT per-(b,t) transpose).
// ---------------------------------------------------------------------------
__global__ __launch_bounds__(256) void k_front(
    const float* __restrict__ h, const float* __restrict__ W1,
    const float* __restrict__ W2, const float* __restrict__ W3,
    const float* __restrict__ A_m, const float* __restrict__ W_add,
    const float* __restrict__ W_mod,
    float* __restrict__ fuv,
    unsigned short* __restrict__ W2bf, unsigned short* __restrict__ W3bf,
    unsigned short* __restrict__ A_mTbf, unsigned short* __restrict__ W_addbf,
    unsigned short* __restrict__ W_modbf, unsigned short* __restrict__ hbfT) {
  __shared__ float hsl[128][65];
  int blk = blockIdx.x, tid = threadIdx.x;
  if (blk < 128) {
    int mtile = blk & 15;            // 32 rows of M=512
    int ntile = blk >> 4;            // 32 cols of N=256
    int lane = tid & 63;
    int w = tid >> 6;
    int lr = lane & 15, lhi = lane >> 4;
    int mh = w & 1, nh = w >> 1;
    int row = mtile * 32 + mh * 16 + lr;     // (b,c): b=row>>7, c=row&127
    int b = row >> 7, c = row & 127;
    int n = ntile * 32 + nh * 16 + lr;       // fuv col
    const float* hb = h + (size_t)b * (NT * NC * ND) + (size_t)c * ND;
    const float* wrow = W1 + (size_t)(n & 127) * (2 * TD) + (n >> 7) * TD;
    f32x4 acc = (f32x4){0.f, 0.f, 0.f, 0.f};
#pragma unroll
    for (int kb = 0; kb < TD; kb += 32) {
      int k0 = kb + lhi * 8;
      int t5 = k0 >> 6, d = k0 & 63;
      const float* ap = hb + (size_t)t5 * (NC * ND) + d;
      short8 a = cvt8(*(const float4*)ap, *(const float4*)(ap + 4));
      const float* bp = wrow + k0;
      short8 bv = cvt8(*(const float4*)bp, *(const float4*)(bp + 4));
      acc = __builtin_amdgcn_mfma_f32_16x16x32_bf16(a, bv, acc, 0, 0, 0);
    }
    int m0 = mtile * 32 + mh * 16 + lhi * 4;
#pragma unroll
    for (int r = 0; r < 4; r++)
      fuv[(size_t)(m0 + r) * 256 + n] = acc[r];
  } else if (blk < 136) {              // W2: 32768 elems
    size_t i = (size_t)(blk - 128) * 4096 + tid * 16;
    conv16(W2 + i, W2bf + i);
  } else if (blk < 140) {              // W3: 16384 elems
    size_t i = (size_t)(blk - 136) * 4096 + tid * 16;
    conv16(W3 + i, W3bf + i);
  } else if (blk < 144) {              // A_m transpose
    size_t base = (size_t)(blk - 140) * 4096 + tid * 16;
    unsigned short tmp[16];
#pragma unroll
    for (int i2 = 0; i2 < 16; i2++) {
      size_t idx = base + i2;
      int v = (int)(idx >> 7), u = (int)(idx & 127);
      tmp[i2] = f2bf(A_m[(size_t)u * 128 + v]);
    }
    *(uint4*)(A_mTbf + base) = *(uint4*)tmp;
    *(uint4*)(A_mTbf + base + 8) = *(uint4*)(tmp + 8);
  } else if (blk < 146) {              // W_add / W_mod
    size_t i = (size_t)tid * 16;
    if (blk == 144) conv16(W_add + i, W_addbf + i);
    else            conv16(W_mod + i, W_modbf + i);
  } else {                             // hbfT: per-(b,t) [d][u]
    int bt = blk - 146;
    const float* hb = h + (size_t)bt * 8192;
    for (int i = tid; i < 8192; i += 256) hsl[i >> 6][i & 63] = hb[i];
    __syncthreads();
    unsigned short* ob = hbfT + (size_t)bt * 8192;
    for (int i = tid; i < 8192; i += 256) {
      int d = i >> 7, u = i & 127;
      ob[i] = f2bf(hsl[u][d]);         // stride-65 LDS read: conflict-free
    }
  }
}

// ---------------------------------------------------------------------------
// Kernel B (MFMA): pairwise MLP -> wTbf[b][v][u].  (verbatim R5)
// ---------------------------------------------------------------------------
__global__ __launch_bounds__(256) void k_pair(
    const float* __restrict__ fuv, const float* __restrict__ b1,
    const unsigned short* __restrict__ W2bf, const float* __restrict__ b2,
    const unsigned short* __restrict__ W3bf, const float* __restrict__ b3,
    const float* __restrict__ W4, const float* __restrict__ b4,
    const float* __restrict__ A_a, unsigned short* __restrict__ wTbf) {
  int blk = blockIdx.x;
  int b = blk >> 7;
  int u = blk & 127;
  __shared__ char x1raw[32768];
  __shared__ char ycraw[4][8192];
  int t = threadIdx.x;
  int lane = t & 63;
  int w = t >> 6;
  const float* fub = fuv + ((size_t)(b * NC + u)) * 256;
  {
    int v = t >> 1;
    int kh2 = (t & 1) << 6;
    const float* fvrow = fuv + ((size_t)(b * NC + v)) * 256 + 128 + kh2;
    const float* fur = fub + kh2;
    const float* b1r = b1 + kh2;
    int sw = (v & 7) << 4;
    int rowbase = v * 256 + kh2 * 2;
    for (int kc = 0; kc < 64; kc += 8) {
      float e[8];
#pragma unroll
      for (int i2 = 0; i2 < 8; i2++) {
        float val = fur[kc + i2] + fvrow[kc + i2] + b1r[kc + i2];
        e[i2] = val > 0.f ? val : 0.f;
      }
      unsigned int pw[4];
#pragma unroll
      for (int i2 = 0; i2 < 4; i2++)
        pw[i2] = (unsigned int)f2bf(e[2 * i2]) |
                 ((unsigned int)f2bf(e[2 * i2 + 1]) << 16);
      *(uint4*)(x1raw + ((rowbase + kc * 2) ^ sw)) =
          make_uint4(pw[0], pw[1], pw[2], pw[3]);
    }
  }
  __syncthreads();
  int v0w = w * 32;
  int lr = lane & 15;
  int lhi = lane >> 4;
  int sw = (lr & 7) << 4;
  char* ycb = ycraw[w];
  f32x4 zacc[2][4];
#pragma unroll
  for (int q = 0; q < 2; q++)
#pragma unroll
    for (int n = 0; n < 4; n++) zacc[q][n] = (f32x4){0.f, 0.f, 0.f, 0.f};
  for (int mc = 0; mc < 256; mc += 64) {
    f32x4 yac[4][2];
#pragma unroll
    for (int mt = 0; mt < 4; mt++) {
      yac[mt][0] = (f32x4){0.f, 0.f, 0.f, 0.f};
      yac[mt][1] = (f32x4){0.f, 0.f, 0.f, 0.f};
    }
#pragma unroll
    for (int ks = 0; ks < 4; ks++) {
      int kb = ks * 32 + lhi * 8;
      int r0 = (v0w + lr) * 256 + kb * 2;
      short8 x0 = *(const short8*)(x1raw + (r0 ^ sw));
      short8 x1v = *(const short8*)(x1raw + ((r0 + 16 * 256) ^ sw));
#pragma unroll
      for (int mt = 0; mt < 4; mt++) {
        const unsigned short* wp = W2bf + (size_t)(mc + mt * 16 + lr) * 128 + kb;
        short8 wv = *(const short8*)wp;
        yac[mt][0] = __builtin_amdgcn_mfma_f32_16x16x32_bf16(wv, x0, yac[mt][0], 0, 0, 0);
        yac[mt][1] = __builtin_amdgcn_mfma_f32_16x16x32_bf16(wv, x1v, yac[mt][1], 0, 0, 0);
      }
    }
#pragma unroll
    for (int mt = 0; mt < 4; mt++) {
      float4 b2v = *(const float4*)(b2 + mc + mt * 16 + lhi * 4);
#pragma unroll
      for (int vg = 0; vg < 2; vg++) {
        int v = vg * 16 + lr;
        float e0 = yac[mt][vg][0] + b2v.x; e0 = e0 > 0.f ? e0 : 0.f;
        float e1 = yac[mt][vg][1] + b2v.y; e1 = e1 > 0.f ? e1 : 0.f;
        float e2 = yac[mt][vg][2] + b2v.z; e2 = e2 > 0.f ? e2 : 0.f;
        float e3 = yac[mt][vg][3] + b2v.w; e3 = e3 > 0.f ? e3 : 0.f;
        uint2 pw;
        pw.x = (unsigned)f2bf(e0) | ((unsigned)f2bf(e1) << 16);
        pw.y = (unsigned)f2bf(e2) | ((unsigned)f2bf(e3) << 16);
        int byte = (v * 128 + (mt * 16 + lhi * 4) * 2) ^ ((lr & 7) << 4);
        *(uint2*)(ycb + byte) = pw;
      }
    }
#pragma unroll
    for (int ks = 0; ks < 2; ks++) {
      int kb = ks * 32 + lhi * 8;
      short8 ya0 = *(const short8*)(ycb + ((lr * 128 + kb * 2) ^ sw));
      short8 ya1 = *(const short8*)(ycb + (((16 + lr) * 128 + kb * 2) ^ sw));
#pragma unroll
      for (int n = 0; n < 4; n++) {
        const unsigned short* wp = W3bf + (size_t)(16 * n + lr) * 256 + mc + kb;
        short8 w3v = *(const short8*)wp;
        zacc[0][n] = __builtin_amdgcn_mfma_f32_16x16x32_bf16(ya0, w3v, zacc[0][n], 0, 0, 0);
        zacc[1][n] = __builtin_amdgcn_mfma_f32_16x16x32_bf16(ya1, w3v, zacc[1][n], 0, 0, 0);
      }
    }
  }
  float sp[2][4];
#pragma unroll
  for (int q = 0; q < 2; q++)
#pragma unroll
    for (int r = 0; r < 4; r++) sp[q][r] = 0.f;
#pragma unroll
  for (int n = 0; n < 4; n++) {
    int j = 16 * n + lr;
    float b3v = b3[j], w4v = W4[j];
#pragma unroll
    for (int q = 0; q < 2; q++)
#pragma unroll
      for (int r = 0; r < 4; r++) {
        float z = zacc[q][n][r] + b3v;
        z = z > 0.f ? z : 0.f;
        sp[q][r] += w4v * z;
      }
  }
#pragma unroll
  for (int mask = 1; mask <= 8; mask <<= 1)
#pragma unroll
    for (int q = 0; q < 2; q++)
#pragma unroll
      for (int r = 0; r < 4; r++)
        sp[q][r] += __shfl_xor(sp[q][r], mask, 64);
  float bb4 = b4[0];
  if (lr == 0) {
#pragma unroll
    for (int q = 0; q < 2; q++)
#pragma unroll
      for (int r = 0; r < 4; r++) {
        int v = v0w + 16 * q + lhi * 4 + r;
        float s = 1.f / (1.f + expf(-(sp[q][r] + bb4)));
        wTbf[((size_t)(b * NC + v)) * NC + u] = f2bf(s * A_a[u * NC + v]);
      }
  }
}

// ---------------------------------------------------------------------------
// Kernel C (MFMA): fused a/m einsums + projections + beta combine. (verbatim R5)
// ---------------------------------------------------------------------------
__global__ __launch_bounds__(64) void k_out_mfma(
    const float* __restrict__ h, const unsigned short* __restrict__ wTbf,
    const unsigned short* __restrict__ A_mTbf,
    const unsigned short* __restrict__ hbfT,
    const unsigned short* __restrict__ W_addbf,
    const unsigned short* __restrict__ W_modbf,
    const float* __restrict__ b_add, const float* __restrict__ b_mod,
    const float* __restrict__ beta1p, const float* __restrict__ beta2p,
    const float* __restrict__ beta3p, float* __restrict__ out) {
  int blk = blockIdx.x;
  int bt = blk >> 3;
  int v0 = (blk & 7) << 4;
  int b = bt / 20;
  __shared__ char apre_l[2048];
  __shared__ char mpre_l[2048];
  int lane = threadIdx.x;
  int lr = lane & 15, lhi = lane >> 4;
  f32x4 aacc[4], macc[4];
#pragma unroll
  for (int nf = 0; nf < 4; nf++) {
    aacc[nf] = (f32x4){0.f, 0.f, 0.f, 0.f};
    macc[nf] = (f32x4){0.f, 0.f, 0.f, 0.f};
  }
  const unsigned short* wrow = wTbf + ((size_t)(b * NC + v0 + lr)) * NC + lhi * 8;
  const unsigned short* arow = A_mTbf + (size_t)(v0 + lr) * NC + lhi * 8;
  const unsigned short* hTrow = hbfT + (size_t)bt * 8192 + lhi * 8;
#pragma unroll
  for (int kb = 0; kb < 128; kb += 32) {
    short8 aw = *(const short8*)(wrow + kb);
    short8 am = *(const short8*)(arow + kb);
#pragma unroll
    for (int nf = 0; nf < 4; nf++) {
      short8 bv = *(const short8*)(hTrow + (size_t)(nf * 16 + lr) * NC + kb);
      aacc[nf] = __builtin_amdgcn_mfma_f32_16x16x32_bf16(aw, bv, aacc[nf], 0, 0, 0);
      macc[nf] = __builtin_amdgcn_mfma_f32_16x16x32_bf16(am, bv, macc[nf], 0, 0, 0);
    }
  }
  float hval[4][4];
  const float* hbase = h + (size_t)bt * 8192;
#pragma unroll
  for (int nf = 0; nf < 4; nf++) {
    int d = nf * 16 + lr;
#pragma unroll
    for (int r = 0; r < 4; r++) {
      int vl = lhi * 4 + r;
      float hv = hbase[(size_t)(v0 + vl) * 64 + d];
      hval[nf][r] = hv;
      int byte = (vl * 128 + d * 2) ^ ((vl & 7) << 4);
      *(unsigned short*)(apre_l + byte) = f2bf(aacc[nf][r]);
      *(unsigned short*)(mpre_l + byte) = f2bf(macc[nf][r] * hv);
    }
  }
  f32x4 oa[4], om[4];
#pragma unroll
  for (int nf = 0; nf < 4; nf++) {
    oa[nf] = (f32x4){0.f, 0.f, 0.f, 0.f};
    om[nf] = (f32x4){0.f, 0.f, 0.f, 0.f};
  }
  int sw = (lr & 7) << 4;
#pragma unroll
  for (int kb = 0; kb < 64; kb += 32) {
    int off0 = lr * 128 + kb * 2 + lhi * 16;
    short8 pa = *(const short8*)(apre_l + (off0 ^ sw));
    short8 pm = *(const short8*)(mpre_l + (off0 ^ sw));
#pragma unroll
    for (int nf = 0; nf < 4; nf++) {
      const unsigned short* wa = W_addbf + (size_t)(nf * 16 + lr) * 64 + kb + lhi * 8;
      const unsigned short* wm = W_modbf + (size_t)(nf * 16 + lr) * 64 + kb + lhi * 8;
      short8 wav = *(const short8*)wa;
      short8 wmv = *(const short8*)wm;
      oa[nf] = __builtin_amdgcn_mfma_f32_16x16x32_bf16(pa, wav, oa[nf], 0, 0, 0);
      om[nf] = __builtin_amdgcn_mfma_f32_16x16x32_bf16(pm, wmv, om[nf], 0, 0, 0);
    }
  }
  float bb1 = beta1p[0], bb2 = beta2p[0], bb3 = beta3p[0];
  float* obase = out + (size_t)bt * 8192 + (size_t)v0 * 64;
#pragma unroll
  for (int nf = 0; nf < 4; nf++) {
    int d = nf * 16 + lr;
    float ba = b_add[d], bm = b_mod[d];
#pragma unroll
    for (int r = 0; r < 4; r++) {
      int vl = lhi * 4 + r;
      obase[(size_t)vl * 64 + d] =
          bb1 * hval[nf][r] + bb2 * (oa[nf][r] + ba) + bb3 * (om[nf][r] + bm);
    }
  }
}

// ---------------------------------------------------------------------------
extern "C" void kernel_launch(void* const* d_in, const int* in_sizes, int n_in,
                              void* d_out, int out_size, void* d_ws, size_t ws_size,
                              hipStream_t stream) {
  const float* h     = (const float*)d_in[0];
  const float* W1    = (const float*)d_in[1];
  const float* b1    = (const float*)d_in[2];
  const float* W2    = (const float*)d_in[3];
  const float* b2    = (const float*)d_in[4];
  const float* W3    = (const float*)d_in[5];
  const float* b3    = (const float*)d_in[6];
  const float* W4    = (const float*)d_in[7];
  const float* b4    = (const float*)d_in[8];
  const float* A_a   = (const float*)d_in[9];
  const float* A_m   = (const float*)d_in[10];
  const float* W_add = (const float*)d_in[11];
  const float* b_add = (const float*)d_in[12];
  const float* W_mod = (const float*)d_in[13];
  const float* b_mod = (const float*)d_in[14];
  const float* beta1 = (const float*)d_in[15];
  const float* beta2 = (const float*)d_in[16];
  const float* beta3 = (const float*)d_in[17];
  float* out = (float*)d_out;

  char* ws = (char*)d_ws;
  float* fuv             = (float*)(ws);                         // 512 KB
  unsigned short* wTbf   = (unsigned short*)(ws + 512 * 1024);   // 128 KB
  unsigned short* A_mTbf = (unsigned short*)(ws + 640 * 1024);   // 32 KB
  unsigned short* W_addbf= (unsigned short*)(ws + 672 * 1024);   // 8 KB
  unsigned short* W_modbf= (unsigned short*)(ws + 680 * 1024);   // 8 KB
  unsigned short* W2bf   = (unsigned short*)(ws + 688 * 1024);   // 64 KB
  unsigned short* W3bf   = (unsigned short*)(ws + 752 * 1024);   // 32 KB
  unsigned short* hbfT   = (unsigned short*)(ws + 784 * 1024);   // 1280 KB

  k_front<<<226, 256, 0, stream>>>(h, W1, W2, W3, A_m, W_add, W_mod,
                                   fuv, W2bf, W3bf, A_mTbf, W_addbf, W_modbf,
                                   hbfT);
  k_pair<<<512, 256, 0, stream>>>(fuv, b1, W2bf, b2, W3bf, b3, W4, b4, A_a, wTbf);
  k_out_mfma<<<640, 64, 0, stream>>>(h, wTbf, A_mTbf, hbfT, W_addbf, W_modbf,
                                     b_add, b_mod, beta1, beta2, beta3, out);
}

// Round 8
// 63.478 us; speedup vs baseline: 4.7338x; 1.0983x over previous
//
#include <hip/hip_runtime.h>
#include <cmath>

#define NB 4
#define NT 20
#define NC 128
#define ND 64
#define TD 1280   // T*D

typedef short short8 __attribute__((ext_vector_type(8)));
typedef float f32x4 __attribute__((ext_vector_type(4)));

static __device__ __forceinline__ unsigned short f2bf(float f) {
  union { float f; unsigned int u; } v; v.f = f;
  unsigned int r = v.u + 0x7FFFu + ((v.u >> 16) & 1u);
  return (unsigned short)(r >> 16);
}

static __device__ __forceinline__ void conv16(const float* __restrict__ s,
                                              unsigned short* __restrict__ d) {
#pragma unroll
  for (int q = 0; q < 2; q++) {
    float4 f0 = *(const float4*)(s + q * 8);
    float4 f1 = *(const float4*)(s + q * 8 + 4);
    uint4 o;
    o.x = (unsigned)f2bf(f0.x) | ((unsigned)f2bf(f0.y) << 16);
    o.y = (unsigned)f2bf(f0.z) | ((unsigned)f2bf(f0.w) << 16);
    o.z = (unsigned)f2bf(f1.x) | ((unsigned)f2bf(f1.y) << 16);
    o.w = (unsigned)f2bf(f1.z) | ((unsigned)f2bf(f1.w) << 16);
    *(uint4*)(d + q * 8) = o;
  }
}

// ---------------------------------------------------------------------------
// D1: conversions needed by the fuv GEMM only (hbf, W1bf).  240 x 256.
// ---------------------------------------------------------------------------
__global__ __launch_bounds__(256) void k_conv_a(
    const float* __restrict__ h, const float* __restrict__ W1,
    unsigned short* __restrict__ hbf, unsigned short* __restrict__ W1bf) {
  int blk = blockIdx.x, tid = threadIdx.x;
  if (blk < 160) {                     // h -> hbf (h_flat [b*C+c][t*D+d])
    int bt = blk >> 1;
    int j = ((blk & 1) << 12) + tid * 16;
    int b = bt / 20;
    int c = j >> 6, d0 = j & 63;
    int t5 = bt - b * 20;
    conv16(h + (size_t)bt * 8192 + j,
           hbf + ((size_t)(b * NC + c)) * TD + t5 * 64 + d0);
  } else {                             // W1: 327680 elems
    size_t i = (size_t)(blk - 160) * 4096 + tid * 16;
    conv16(W1 + i, W1bf + i);
  }
}

// ---------------------------------------------------------------------------
// D2: fuv GEMM (no split-K) + remaining conversions as extra blocks.
//  blk <256 : fuv = h_flat @ [W1u|W1v]^T.  M=512,N=256,K=1280.
//             block = M32 x N16; 2 waves, wave = M16 x N16, 40 MFMAs.
//  blk 256+ : W2,W3,A_mT,W_add,W_mod,hbfT conversions (needed by D3/D4 only).
// ---------------------------------------------------------------------------
__global__ __launch_bounds__(128) void k_fuv2(
    const unsigned short* __restrict__ hbf,
    const unsigned short* __restrict__ W1bf,
    const float* __restrict__ h, const float* __restrict__ W2,
    const float* __restrict__ W3, const float* __restrict__ A_m,
    const float* __restrict__ W_add, const float* __restrict__ W_mod,
    float* __restrict__ fuv,
    unsigned short* __restrict__ W2bf, unsigned short* __restrict__ W3bf,
    unsigned short* __restrict__ A_mTbf, unsigned short* __restrict__ W_addbf,
    unsigned short* __restrict__ W_modbf, unsigned short* __restrict__ hbfT) {
  __shared__ float hsl[128][65];
  int blk = blockIdx.x, tid = threadIdx.x;
  if (blk < 256) {
    int mtile = blk & 15;              // 16 tiles of M32
    int ntile = blk >> 4;              // 16 tiles of N16
    int lane = tid & 63;
    int w = tid >> 6;
    int lr = lane & 15, lhi = lane >> 4;
    int row = mtile * 32 + w * 16 + lr;
    const unsigned short* ap = hbf + (size_t)row * TD + lhi * 8;
    int n = ntile * 16 + lr;
    const unsigned short* bp =
        W1bf + (size_t)(n & 127) * (2 * TD) + (n >> 7) * TD + lhi * 8;
    f32x4 acc = (f32x4){0.f, 0.f, 0.f, 0.f};
#pragma unroll 4
    for (int kb = 0; kb < TD; kb += 32) {
      short8 a = *(const short8*)(ap + kb);
      short8 bv = *(const short8*)(bp + kb);
      acc = __builtin_amdgcn_mfma_f32_16x16x32_bf16(a, bv, acc, 0, 0, 0);
    }
    int m0 = mtile * 32 + w * 16 + lhi * 4;
#pragma unroll
    for (int r = 0; r < 4; r++)
      fuv[(size_t)(m0 + r) * 256 + n] = acc[r];
    return;
  }
  int cb = blk - 256;
  if (cb < 16) {                       // W2: 32768 elems, 2048/block
    size_t i = (size_t)cb * 2048 + tid * 16;
    conv16(W2 + i, W2bf + i);
  } else if (cb < 24) {                // W3: 16384 elems
    size_t i = (size_t)(cb - 16) * 2048 + tid * 16;
    conv16(W3 + i, W3bf + i);
  } else if (cb < 32) {                // A_m transpose: 16384 elems
    size_t base = (size_t)(cb - 24) * 2048 + tid * 16;
    unsigned short tmp[16];
#pragma unroll
    for (int i2 = 0; i2 < 16; i2++) {
      size_t idx = base + i2;
      int v = (int)(idx >> 7), u = (int)(idx & 127);
      tmp[i2] = f2bf(A_m[(size_t)u * 128 + v]);
    }
    *(uint4*)(A_mTbf + base) = *(uint4*)tmp;
    *(uint4*)(A_mTbf + base + 8) = *(uint4*)(tmp + 8);
  } else if (cb < 34) {                // W_add: 4096 elems, 2 blocks
    size_t i = (size_t)(cb - 32) * 2048 + tid * 16;
    conv16(W_add + i, W_addbf + i);
  } else if (cb < 36) {                // W_mod
    size_t i = (size_t)(cb - 34) * 2048 + tid * 16;
    conv16(W_mod + i, W_modbf + i);
  } else {                             // hbfT: per-(b,t) [d][u], 80 blocks
    int bt = cb - 36;
    const float* hb = h + (size_t)bt * 8192;
    for (int i = tid; i < 8192; i += 128) hsl[i >> 6][i & 63] = hb[i];
    __syncthreads();
    unsigned short* ob = hbfT + (size_t)bt * 8192;
    for (int i = tid; i < 8192; i += 128) {
      int d = i >> 7, u = i & 127;
      ob[i] = f2bf(hsl[u][d]);         // stride-65 LDS read: conflict-free
    }
  }
}

// ---------------------------------------------------------------------------
// D3: pairwise MLP -> wTbf[b][v][u].  (R5 body; ycraw right-sized 8K->4K,
// LDS 64->48 KB => 3 blocks/CU.)
// ---------------------------------------------------------------------------
__global__ __launch_bounds__(256) void k_pair(
    const float* __restrict__ fuv, const float* __restrict__ b1,
    const unsigned short* __restrict__ W2bf, const float* __restrict__ b2,
    const unsigned short* __restrict__ W3bf, const float* __restrict__ b3,
    const float* __restrict__ W4, const float* __restrict__ b4,
    const float* __restrict__ A_a, unsigned short* __restrict__ wTbf) {
  int blk = blockIdx.x;
  int b = blk >> 7;
  int u = blk & 127;
  __shared__ char x1raw[32768];
  __shared__ char ycraw[4][4096];
  int t = threadIdx.x;
  int lane = t & 63;
  int w = t >> 6;
  const float* fub = fuv + ((size_t)(b * NC + u)) * 256;
  {
    int v = t >> 1;
    int kh2 = (t & 1) << 6;
    const float* fvrow = fuv + ((size_t)(b * NC + v)) * 256 + 128 + kh2;
    const float* fur = fub + kh2;
    const float* b1r = b1 + kh2;
    int sw = (v & 7) << 4;
    int rowbase = v * 256 + kh2 * 2;
    for (int kc = 0; kc < 64; kc += 8) {
      float e[8];
#pragma unroll
      for (int i2 = 0; i2 < 8; i2++) {
        float val = fur[kc + i2] + fvrow[kc + i2] + b1r[kc + i2];
        e[i2] = val > 0.f ? val : 0.f;
      }
      unsigned int pw[4];
#pragma unroll
      for (int i2 = 0; i2 < 4; i2++)
        pw[i2] = (unsigned int)f2bf(e[2 * i2]) |
                 ((unsigned int)f2bf(e[2 * i2 + 1]) << 16);
      *(uint4*)(x1raw + ((rowbase + kc * 2) ^ sw)) =
          make_uint4(pw[0], pw[1], pw[2], pw[3]);
    }
  }
  __syncthreads();
  int v0w = w * 32;
  int lr = lane & 15;
  int lhi = lane >> 4;
  int sw = (lr & 7) << 4;
  char* ycb = ycraw[w];
  f32x4 zacc[2][4];
#pragma unroll
  for (int q = 0; q < 2; q++)
#pragma unroll
    for (int n = 0; n < 4; n++) zacc[q][n] = (f32x4){0.f, 0.f, 0.f, 0.f};
  for (int mc = 0; mc < 256; mc += 64) {
    f32x4 yac[4][2];
#pragma unroll
    for (int mt = 0; mt < 4; mt++) {
      yac[mt][0] = (f32x4){0.f, 0.f, 0.f, 0.f};
      yac[mt][1] = (f32x4){0.f, 0.f, 0.f, 0.f};
    }
#pragma unroll
    for (int ks = 0; ks < 4; ks++) {
      int kb = ks * 32 + lhi * 8;
      int r0 = (v0w + lr) * 256 + kb * 2;
      short8 x0 = *(const short8*)(x1raw + (r0 ^ sw));
      short8 x1v = *(const short8*)(x1raw + ((r0 + 16 * 256) ^ sw));
#pragma unroll
      for (int mt = 0; mt < 4; mt++) {
        const unsigned short* wp = W2bf + (size_t)(mc + mt * 16 + lr) * 128 + kb;
        short8 wv = *(const short8*)wp;
        yac[mt][0] = __builtin_amdgcn_mfma_f32_16x16x32_bf16(wv, x0, yac[mt][0], 0, 0, 0);
        yac[mt][1] = __builtin_amdgcn_mfma_f32_16x16x32_bf16(wv, x1v, yac[mt][1], 0, 0, 0);
      }
    }
#pragma unroll
    for (int mt = 0; mt < 4; mt++) {
      float4 b2v = *(const float4*)(b2 + mc + mt * 16 + lhi * 4);
#pragma unroll
      for (int vg = 0; vg < 2; vg++) {
        int v = vg * 16 + lr;
        float e0 = yac[mt][vg][0] + b2v.x; e0 = e0 > 0.f ? e0 : 0.f;
        float e1 = yac[mt][vg][1] + b2v.y; e1 = e1 > 0.f ? e1 : 0.f;
        float e2 = yac[mt][vg][2] + b2v.z; e2 = e2 > 0.f ? e2 : 0.f;
        float e3 = yac[mt][vg][3] + b2v.w; e3 = e3 > 0.f ? e3 : 0.f;
        uint2 pw;
        pw.x = (unsigned)f2bf(e0) | ((unsigned)f2bf(e1) << 16);
        pw.y = (unsigned)f2bf(e2) | ((unsigned)f2bf(e3) << 16);
        int byte = (v * 128 + (mt * 16 + lhi * 4) * 2) ^ ((lr & 7) << 4);
        *(uint2*)(ycb + byte) = pw;
      }
    }
#pragma unroll
    for (int ks = 0; ks < 2; ks++) {
      int kb = ks * 32 + lhi * 8;
      short8 ya0 = *(const short8*)(ycb + ((lr * 128 + kb * 2) ^ sw));
      short8 ya1 = *(const short8*)(ycb + (((16 + lr) * 128 + kb * 2) ^ sw));
#pragma unroll
      for (int n = 0; n < 4; n++) {
        const unsigned short* wp = W3bf + (size_t)(16 * n + lr) * 256 + mc + kb;
        short8 w3v = *(const short8*)wp;
        zacc[0][n] = __builtin_amdgcn_mfma_f32_16x16x32_bf16(ya0, w3v, zacc[0][n], 0, 0, 0);
        zacc[1][n] = __builtin_amdgcn_mfma_f32_16x16x32_bf16(ya1, w3v, zacc[1][n], 0, 0, 0);
      }
    }
  }
  float sp[2][4];
#pragma unroll
  for (int q = 0; q < 2; q++)
#pragma unroll
    for (int r = 0; r < 4; r++) sp[q][r] = 0.f;
#pragma unroll
  for (int n = 0; n < 4; n++) {
    int j = 16 * n + lr;
    float b3v = b3[j], w4v = W4[j];
#pragma unroll
    for (int q = 0; q < 2; q++)
#pragma unroll
      for (int r = 0; r < 4; r++) {
        float z = zacc[q][n][r] + b3v;
        z = z > 0.f ? z : 0.f;
        sp[q][r] += w4v * z;
      }
  }
#pragma unroll
  for (int mask = 1; mask <= 8; mask <<= 1)
#pragma unroll
    for (int q = 0; q < 2; q++)
#pragma unroll
      for (int r = 0; r < 4; r++)
        sp[q][r] += __shfl_xor(sp[q][r], mask, 64);
  float bb4 = b4[0];
  if (lr == 0) {
#pragma unroll
    for (int q = 0; q < 2; q++)
#pragma unroll
      for (int r = 0; r < 4; r++) {
        int v = v0w + 16 * q + lhi * 4 + r;
        float s = 1.f / (1.f + expf(-(sp[q][r] + bb4)));
        wTbf[((size_t)(b * NC + v)) * NC + u] = f2bf(s * A_a[u * NC + v]);
      }
  }
}

// ---------------------------------------------------------------------------
// D4: fused a/m einsums + projections + beta combine.  (verbatim R5)
// ---------------------------------------------------------------------------
__global__ __launch_bounds__(64) void k_out_mfma(
    const float* __restrict__ h, const unsigned short* __restrict__ wTbf,
    const unsigned short* __restrict__ A_mTbf,
    const unsigned short* __restrict__ hbfT,
    const unsigned short* __restrict__ W_addbf,
    const unsigned short* __restrict__ W_modbf,
    const float* __restrict__ b_add, const float* __restrict__ b_mod,
    const float* __restrict__ beta1p, const float* __restrict__ beta2p,
    const float* __restrict__ beta3p, float* __restrict__ out) {
  int blk = blockIdx.x;
  int bt = blk >> 3;
  int v0 = (blk & 7) << 4;
  int b = bt / 20;
  __shared__ char apre_l[2048];
  __shared__ char mpre_l[2048];
  int lane = threadIdx.x;
  int lr = lane & 15, lhi = lane >> 4;
  f32x4 aacc[4], macc[4];
#pragma unroll
  for (int nf = 0; nf < 4; nf++) {
    aacc[nf] = (f32x4){0.f, 0.f, 0.f, 0.f};
    macc[nf] = (f32x4){0.f, 0.f, 0.f, 0.f};
  }
  const unsigned short* wrow = wTbf + ((size_t)(b * NC + v0 + lr)) * NC + lhi * 8;
  const unsigned short* arow = A_mTbf + (size_t)(v0 + lr) * NC + lhi * 8;
  const unsigned short* hTrow = hbfT + (size_t)bt * 8192 + lhi * 8;
#pragma unroll
  for (int kb = 0; kb < 128; kb += 32) {
    short8 aw = *(const short8*)(wrow + kb);
    short8 am = *(const short8*)(arow + kb);
#pragma unroll
    for (int nf = 0; nf < 4; nf++) {
      short8 bv = *(const short8*)(hTrow + (size_t)(nf * 16 + lr) * NC + kb);
      aacc[nf] = __builtin_amdgcn_mfma_f32_16x16x32_bf16(aw, bv, aacc[nf], 0, 0, 0);
      macc[nf] = __builtin_amdgcn_mfma_f32_16x16x32_bf16(am, bv, macc[nf], 0, 0, 0);
    }
  }
  float hval[4][4];
  const float* hbase = h + (size_t)bt * 8192;
#pragma unroll
  for (int nf = 0; nf < 4; nf++) {
    int d = nf * 16 + lr;
#pragma unroll
    for (int r = 0; r < 4; r++) {
      int vl = lhi * 4 + r;
      float hv = hbase[(size_t)(v0 + vl) * 64 + d];
      hval[nf][r] = hv;
      int byte = (vl * 128 + d * 2) ^ ((vl & 7) << 4);
      *(unsigned short*)(apre_l + byte) = f2bf(aacc[nf][r]);
      *(unsigned short*)(mpre_l + byte) = f2bf(macc[nf][r] * hv);
    }
  }
  f32x4 oa[4], om[4];
#pragma unroll
  for (int nf = 0; nf < 4; nf++) {
    oa[nf] = (f32x4){0.f, 0.f, 0.f, 0.f};
    om[nf] = (f32x4){0.f, 0.f, 0.f, 0.f};
  }
  int sw = (lr & 7) << 4;
#pragma unroll
  for (int kb = 0; kb < 64; kb += 32) {
    int off0 = lr * 128 + kb * 2 + lhi * 16;
    short8 pa = *(const short8*)(apre_l + (off0 ^ sw));
    short8 pm = *(const short8*)(mpre_l + (off0 ^ sw));
#pragma unroll
    for (int nf = 0; nf < 4; nf++) {
      const unsigned short* wa = W_addbf + (size_t)(nf * 16 + lr) * 64 + kb + lhi * 8;
      const unsigned short* wm = W_modbf + (size_t)(nf * 16 + lr) * 64 + kb + lhi * 8;
      short8 wav = *(const short8*)wa;
      short8 wmv = *(const short8*)wm;
      oa[nf] = __builtin_amdgcn_mfma_f32_16x16x32_bf16(pa, wav, oa[nf], 0, 0, 0);
      om[nf] = __builtin_amdgcn_mfma_f32_16x16x32_bf16(pm, wmv, om[nf], 0, 0, 0);
    }
  }
  float bb1 = beta1p[0], bb2 = beta2p[0], bb3 = beta3p[0];
  float* obase = out + (size_t)bt * 8192 + (size_t)v0 * 64;
#pragma unroll
  for (int nf = 0; nf < 4; nf++) {
    int d = nf * 16 + lr;
    float ba = b_add[d], bm = b_mod[d];
#pragma unroll
    for (int r = 0; r < 4; r++) {
      int vl = lhi * 4 + r;
      obase[(size_t)vl * 64 + d] =
          bb1 * hval[nf][r] + bb2 * (oa[nf][r] + ba) + bb3 * (om[nf][r] + bm);
    }
  }
}

// ---------------------------------------------------------------------------
extern "C" void kernel_launch(void* const* d_in, const int* in_sizes, int n_in,
                              void* d_out, int out_size, void* d_ws, size_t ws_size,
                              hipStream_t stream) {
  const float* h     = (const float*)d_in[0];
  const float* W1    = (const float*)d_in[1];
  const float* b1    = (const float*)d_in[2];
  const float* W2    = (const float*)d_in[3];
  const float* b2    = (const float*)d_in[4];
  const float* W3    = (const float*)d_in[5];
  const float* b3    = (const float*)d_in[6];
  const float* W4    = (const float*)d_in[7];
  const float* b4    = (const float*)d_in[8];
  const float* A_a   = (const float*)d_in[9];
  const float* A_m   = (const float*)d_in[10];
  const float* W_add = (const float*)d_in[11];
  const float* b_add = (const float*)d_in[12];
  const float* W_mod = (const float*)d_in[13];
  const float* b_mod = (const float*)d_in[14];
  const float* beta1 = (const float*)d_in[15];
  const float* beta2 = (const float*)d_in[16];
  const float* beta3 = (const float*)d_in[17];
  float* out = (float*)d_out;

  char* ws = (char*)d_ws;
  float* fuv             = (float*)(ws);                         // 512 KB
  unsigned short* wTbf   = (unsigned short*)(ws + 512 * 1024);   // 128 KB
  unsigned short* A_mTbf = (unsigned short*)(ws + 640 * 1024);   // 32 KB
  unsigned short* W_addbf= (unsigned short*)(ws + 672 * 1024);   // 8 KB
  unsigned short* W_modbf= (unsigned short*)(ws + 680 * 1024);   // 8 KB
  unsigned short* W2bf   = (unsigned short*)(ws + 688 * 1024);   // 64 KB
  unsigned short* W3bf   = (unsigned short*)(ws + 752 * 1024);   // 32 KB
  unsigned short* W1bf   = (unsigned short*)(ws + 784 * 1024);   // 640 KB
  unsigned short* hbf    = (unsigned short*)(ws + 1424 * 1024);  // 1280 KB
  unsigned short* hbfT   = (unsigned short*)(ws + 2704 * 1024);  // 1280 KB

  k_conv_a<<<240, 256, 0, stream>>>(h, W1, hbf, W1bf);
  k_fuv2<<<372, 128, 0, stream>>>(hbf, W1bf, h, W2, W3, A_m, W_add, W_mod,
                                  fuv, W2bf, W3bf, A_mTbf, W_addbf, W_modbf,
                                  hbfT);
  k_pair<<<512, 256, 0, stream>>>(fuv, b1, W2bf, b2, W3bf, b3, W4, b4, A_a, wTbf);
  k_out_mfma<<<640, 64, 0, stream>>>(h, wTbf, A_mTbf, hbfT, W_addbf, W_modbf,
                                     b_add, b_mod, beta1, beta2, beta3, out);
}

// Round 9
// 58.961 us; speedup vs baseline: 5.0966x; 1.0766x over previous
//
#include <hip/hip_runtime.h>
#include <cmath>

#define NB 4
#define NT 20
#define NC 128
#define ND 64
#define TD 1280   // T*D

typedef short short8 __attribute__((ext_vector_type(8)));
typedef float f32x4 __attribute__((ext_vector_type(4)));

static __device__ __forceinline__ unsigned short f2bf(float f) {
  union { float f; unsigned int u; } v; v.f = f;
  unsigned int r = v.u + 0x7FFFu + ((v.u >> 16) & 1u);
  return (unsigned short)(r >> 16);
}

static __device__ __forceinline__ void conv16(const float* __restrict__ s,
                                              unsigned short* __restrict__ d) {
#pragma unroll
  for (int q = 0; q < 2; q++) {
    float4 f0 = *(const float4*)(s + q * 8);
    float4 f1 = *(const float4*)(s + q * 8 + 4);
    uint4 o;
    o.x = (unsigned)f2bf(f0.x) | ((unsigned)f2bf(f0.y) << 16);
    o.y = (unsigned)f2bf(f0.z) | ((unsigned)f2bf(f0.w) << 16);
    o.z = (unsigned)f2bf(f1.x) | ((unsigned)f2bf(f1.y) << 16);
    o.w = (unsigned)f2bf(f1.z) | ((unsigned)f2bf(f1.w) << 16);
    *(uint4*)(d + q * 8) = o;
  }
}

// ---------------------------------------------------------------------------
// D1: conversions needed by the fuv GEMM only (hbf, W1bf).  240 x 256.
// ---------------------------------------------------------------------------
__global__ __launch_bounds__(256) void k_conv_a(
    const float* __restrict__ h, const float* __restrict__ W1,
    unsigned short* __restrict__ hbf, unsigned short* __restrict__ W1bf) {
  int blk = blockIdx.x, tid = threadIdx.x;
  if (blk < 160) {                     // h -> hbf (h_flat [b*C+c][t*D+d])
    int bt = blk >> 1;
    int j = ((blk & 1) << 12) + tid * 16;
    int b = bt / 20;
    int c = j >> 6, d0 = j & 63;
    int t5 = bt - b * 20;
    conv16(h + (size_t)bt * 8192 + j,
           hbf + ((size_t)(b * NC + c)) * TD + t5 * 64 + d0);
  } else {                             // W1: 327680 elems
    size_t i = (size_t)(blk - 160) * 4096 + tid * 16;
    conv16(W1 + i, W1bf + i);
  }
}

// ---------------------------------------------------------------------------
// D2: fuv GEMM (no split-K) + remaining conversions as extra blocks.
// ---------------------------------------------------------------------------
__global__ __launch_bounds__(128) void k_fuv2(
    const unsigned short* __restrict__ hbf,
    const unsigned short* __restrict__ W1bf,
    const float* __restrict__ h, const float* __restrict__ W2,
    const float* __restrict__ W3, const float* __restrict__ A_m,
    const float* __restrict__ W_add, const float* __restrict__ W_mod,
    float* __restrict__ fuv,
    unsigned short* __restrict__ W2bf, unsigned short* __restrict__ W3bf,
    unsigned short* __restrict__ A_mTbf, unsigned short* __restrict__ W_addbf,
    unsigned short* __restrict__ W_modbf, unsigned short* __restrict__ hbfT) {
  __shared__ float hsl[128][65];
  int blk = blockIdx.x, tid = threadIdx.x;
  if (blk < 256) {
    int mtile = blk & 15;
    int ntile = blk >> 4;
    int lane = tid & 63;
    int w = tid >> 6;
    int lr = lane & 15, lhi = lane >> 4;
    int row = mtile * 32 + w * 16 + lr;
    const unsigned short* ap = hbf + (size_t)row * TD + lhi * 8;
    int n = ntile * 16 + lr;
    const unsigned short* bp =
        W1bf + (size_t)(n & 127) * (2 * TD) + (n >> 7) * TD + lhi * 8;
    f32x4 acc = (f32x4){0.f, 0.f, 0.f, 0.f};
#pragma unroll 4
    for (int kb = 0; kb < TD; kb += 32) {
      short8 a = *(const short8*)(ap + kb);
      short8 bv = *(const short8*)(bp + kb);
      acc = __builtin_amdgcn_mfma_f32_16x16x32_bf16(a, bv, acc, 0, 0, 0);
    }
    int m0 = mtile * 32 + w * 16 + lhi * 4;
#pragma unroll
    for (int r = 0; r < 4; r++)
      fuv[(size_t)(m0 + r) * 256 + n] = acc[r];
    return;
  }
  int cb = blk - 256;
  if (cb < 16) {
    size_t i = (size_t)cb * 2048 + tid * 16;
    conv16(W2 + i, W2bf + i);
  } else if (cb < 24) {
    size_t i = (size_t)(cb - 16) * 2048 + tid * 16;
    conv16(W3 + i, W3bf + i);
  } else if (cb < 32) {
    size_t base = (size_t)(cb - 24) * 2048 + tid * 16;
    unsigned short tmp[16];
#pragma unroll
    for (int i2 = 0; i2 < 16; i2++) {
      size_t idx = base + i2;
      int v = (int)(idx >> 7), u = (int)(idx & 127);
      tmp[i2] = f2bf(A_m[(size_t)u * 128 + v]);
    }
    *(uint4*)(A_mTbf + base) = *(uint4*)tmp;
    *(uint4*)(A_mTbf + base + 8) = *(uint4*)(tmp + 8);
  } else if (cb < 34) {
    size_t i = (size_t)(cb - 32) * 2048 + tid * 16;
    conv16(W_add + i, W_addbf + i);
  } else if (cb < 36) {
    size_t i = (size_t)(cb - 34) * 2048 + tid * 16;
    conv16(W_mod + i, W_modbf + i);
  } else {
    int bt = cb - 36;
    const float* hb = h + (size_t)bt * 8192;
    for (int i = tid; i < 8192; i += 128) hsl[i >> 6][i & 63] = hb[i];
    __syncthreads();
    unsigned short* ob = hbfT + (size_t)bt * 8192;
    for (int i = tid; i < 8192; i += 128) {
      int d = i >> 7, u = i & 127;
      ob[i] = f2bf(hsl[u][d]);
    }
  }
}

// ---------------------------------------------------------------------------
// D3: pairwise MLP -> wTbf[b][v][u].
// NEW: per-mc weight fragments batch-loaded into registers (16 W2 + 8 W3
// short8's, static-indexed) BEFORE the MFMA clusters -> one L2 latency wait
// covers 24 loads instead of 24 serialized waits.
// ---------------------------------------------------------------------------
__global__ __launch_bounds__(256) void k_pair(
    const float* __restrict__ fuv, const float* __restrict__ b1,
    const unsigned short* __restrict__ W2bf, const float* __restrict__ b2,
    const unsigned short* __restrict__ W3bf, const float* __restrict__ b3,
    const float* __restrict__ W4, const float* __restrict__ b4,
    const float* __restrict__ A_a, unsigned short* __restrict__ wTbf) {
  int blk = blockIdx.x;
  int b = blk >> 7;
  int u = blk & 127;
  __shared__ char x1raw[32768];
  __shared__ char ycraw[4][4096];
  int t = threadIdx.x;
  int lane = t & 63;
  int w = t >> 6;
  const float* fub = fuv + ((size_t)(b * NC + u)) * 256;
  {
    int v = t >> 1;
    int kh2 = (t & 1) << 6;
    const float* fvrow = fuv + ((size_t)(b * NC + v)) * 256 + 128 + kh2;
    const float* fur = fub + kh2;
    const float* b1r = b1 + kh2;
    int sw = (v & 7) << 4;
    int rowbase = v * 256 + kh2 * 2;
    for (int kc = 0; kc < 64; kc += 8) {
      float e[8];
#pragma unroll
      for (int i2 = 0; i2 < 8; i2++) {
        float val = fur[kc + i2] + fvrow[kc + i2] + b1r[kc + i2];
        e[i2] = val > 0.f ? val : 0.f;
      }
      unsigned int pw[4];
#pragma unroll
      for (int i2 = 0; i2 < 4; i2++)
        pw[i2] = (unsigned int)f2bf(e[2 * i2]) |
                 ((unsigned int)f2bf(e[2 * i2 + 1]) << 16);
      *(uint4*)(x1raw + ((rowbase + kc * 2) ^ sw)) =
          make_uint4(pw[0], pw[1], pw[2], pw[3]);
    }
  }
  __syncthreads();
  int v0w = w * 32;
  int lr = lane & 15;
  int lhi = lane >> 4;
  int sw = (lr & 7) << 4;
  char* ycb = ycraw[w];
  f32x4 zacc[2][4];
#pragma unroll
  for (int q = 0; q < 2; q++)
#pragma unroll
    for (int n = 0; n < 4; n++) zacc[q][n] = (f32x4){0.f, 0.f, 0.f, 0.f};

  const unsigned short* w2base = W2bf + (size_t)lr * 128 + lhi * 8;
  const unsigned short* w3base = W3bf + (size_t)lr * 256 + lhi * 8;

  for (int mc = 0; mc < 256; mc += 64) {
    // --- batch-issue all weight fragment loads for this chunk ---
    short8 w2f[16];   // [ks*4 + mt]
#pragma unroll
    for (int ks = 0; ks < 4; ks++)
#pragma unroll
      for (int mt = 0; mt < 4; mt++)
        w2f[ks * 4 + mt] =
            *(const short8*)(w2base + (size_t)(mc + mt * 16) * 128 + ks * 32);
    short8 w3f[8];    // [ks*4 + n]
#pragma unroll
    for (int ks = 0; ks < 2; ks++)
#pragma unroll
      for (int n = 0; n < 4; n++)
        w3f[ks * 4 + n] =
            *(const short8*)(w3base + (size_t)(16 * n) * 256 + mc + ks * 32);

    // --- GEMM1: C[m][v] = W2 @ X1^T ---
    f32x4 yac[4][2];
#pragma unroll
    for (int mt = 0; mt < 4; mt++) {
      yac[mt][0] = (f32x4){0.f, 0.f, 0.f, 0.f};
      yac[mt][1] = (f32x4){0.f, 0.f, 0.f, 0.f};
    }
#pragma unroll
    for (int ks = 0; ks < 4; ks++) {
      int kb = ks * 32 + lhi * 8;
      int r0 = (v0w + lr) * 256 + kb * 2;
      short8 x0 = *(const short8*)(x1raw + (r0 ^ sw));
      short8 x1v = *(const short8*)(x1raw + ((r0 + 16 * 256) ^ sw));
#pragma unroll
      for (int mt = 0; mt < 4; mt++) {
        yac[mt][0] = __builtin_amdgcn_mfma_f32_16x16x32_bf16(w2f[ks * 4 + mt], x0, yac[mt][0], 0, 0, 0);
        yac[mt][1] = __builtin_amdgcn_mfma_f32_16x16x32_bf16(w2f[ks * 4 + mt], x1v, yac[mt][1], 0, 0, 0);
      }
    }
    // --- bias + relu + pack: one b64 store per (mt, vgrp) ---
#pragma unroll
    for (int mt = 0; mt < 4; mt++) {
      float4 b2v = *(const float4*)(b2 + mc + mt * 16 + lhi * 4);
#pragma unroll
      for (int vg = 0; vg < 2; vg++) {
        int v = vg * 16 + lr;
        float e0 = yac[mt][vg][0] + b2v.x; e0 = e0 > 0.f ? e0 : 0.f;
        float e1 = yac[mt][vg][1] + b2v.y; e1 = e1 > 0.f ? e1 : 0.f;
        float e2 = yac[mt][vg][2] + b2v.z; e2 = e2 > 0.f ? e2 : 0.f;
        float e3 = yac[mt][vg][3] + b2v.w; e3 = e3 > 0.f ? e3 : 0.f;
        uint2 pw;
        pw.x = (unsigned)f2bf(e0) | ((unsigned)f2bf(e1) << 16);
        pw.y = (unsigned)f2bf(e2) | ((unsigned)f2bf(e3) << 16);
        int byte = (v * 128 + (mt * 16 + lhi * 4) * 2) ^ ((lr & 7) << 4);
        *(uint2*)(ycb + byte) = pw;
      }
    }
    // --- GEMM2 partial: Z += Yc @ W3[:, mc:mc+64]^T ---
#pragma unroll
    for (int ks = 0; ks < 2; ks++) {
      int kb = ks * 32 + lhi * 8;
      short8 ya0 = *(const short8*)(ycb + ((lr * 128 + kb * 2) ^ sw));
      short8 ya1 = *(const short8*)(ycb + (((16 + lr) * 128 + kb * 2) ^ sw));
#pragma unroll
      for (int n = 0; n < 4; n++) {
        zacc[0][n] = __builtin_amdgcn_mfma_f32_16x16x32_bf16(ya0, w3f[ks * 4 + n], zacc[0][n], 0, 0, 0);
        zacc[1][n] = __builtin_amdgcn_mfma_f32_16x16x32_bf16(ya1, w3f[ks * 4 + n], zacc[1][n], 0, 0, 0);
      }
    }
  }
  float sp[2][4];
#pragma unroll
  for (int q = 0; q < 2; q++)
#pragma unroll
    for (int r = 0; r < 4; r++) sp[q][r] = 0.f;
#pragma unroll
  for (int n = 0; n < 4; n++) {
    int j = 16 * n + lr;
    float b3v = b3[j], w4v = W4[j];
#pragma unroll
    for (int q = 0; q < 2; q++)
#pragma unroll
      for (int r = 0; r < 4; r++) {
        float z = zacc[q][n][r] + b3v;
        z = z > 0.f ? z : 0.f;
        sp[q][r] += w4v * z;
      }
  }
#pragma unroll
  for (int mask = 1; mask <= 8; mask <<= 1)
#pragma unroll
    for (int q = 0; q < 2; q++)
#pragma unroll
      for (int r = 0; r < 4; r++)
        sp[q][r] += __shfl_xor(sp[q][r], mask, 64);
  float bb4 = b4[0];
  if (lr == 0) {
#pragma unroll
    for (int q = 0; q < 2; q++)
#pragma unroll
      for (int r = 0; r < 4; r++) {
        int v = v0w + 16 * q + lhi * 4 + r;
        float s = 1.f / (1.f + expf(-(sp[q][r] + bb4)));
        wTbf[((size_t)(b * NC + v)) * NC + u] = f2bf(s * A_a[u * NC + v]);
      }
  }
}

// ---------------------------------------------------------------------------
// D4: fused a/m einsums + projections + beta combine.  (verbatim)
// ---------------------------------------------------------------------------
__global__ __launch_bounds__(64) void k_out_mfma(
    const float* __restrict__ h, const unsigned short* __restrict__ wTbf,
    const unsigned short* __restrict__ A_mTbf,
    const unsigned short* __restrict__ hbfT,
    const unsigned short* __restrict__ W_addbf,
    const unsigned short* __restrict__ W_modbf,
    const float* __restrict__ b_add, const float* __restrict__ b_mod,
    const float* __restrict__ beta1p, const float* __restrict__ beta2p,
    const float* __restrict__ beta3p, float* __restrict__ out) {
  int blk = blockIdx.x;
  int bt = blk >> 3;
  int v0 = (blk & 7) << 4;
  int b = bt / 20;
  __shared__ char apre_l[2048];
  __shared__ char mpre_l[2048];
  int lane = threadIdx.x;
  int lr = lane & 15, lhi = lane >> 4;
  f32x4 aacc[4], macc[4];
#pragma unroll
  for (int nf = 0; nf < 4; nf++) {
    aacc[nf] = (f32x4){0.f, 0.f, 0.f, 0.f};
    macc[nf] = (f32x4){0.f, 0.f, 0.f, 0.f};
  }
  const unsigned short* wrow = wTbf + ((size_t)(b * NC + v0 + lr)) * NC + lhi * 8;
  const unsigned short* arow = A_mTbf + (size_t)(v0 + lr) * NC + lhi * 8;
  const unsigned short* hTrow = hbfT + (size_t)bt * 8192 + lhi * 8;
#pragma unroll
  for (int kb = 0; kb < 128; kb += 32) {
    short8 aw = *(const short8*)(wrow + kb);
    short8 am = *(const short8*)(arow + kb);
#pragma unroll
    for (int nf = 0; nf < 4; nf++) {
      short8 bv = *(const short8*)(hTrow + (size_t)(nf * 16 + lr) * NC + kb);
      aacc[nf] = __builtin_amdgcn_mfma_f32_16x16x32_bf16(aw, bv, aacc[nf], 0, 0, 0);
      macc[nf] = __builtin_amdgcn_mfma_f32_16x16x32_bf16(am, bv, macc[nf], 0, 0, 0);
    }
  }
  float hval[4][4];
  const float* hbase = h + (size_t)bt * 8192;
#pragma unroll
  for (int nf = 0; nf < 4; nf++) {
    int d = nf * 16 + lr;
#pragma unroll
    for (int r = 0; r < 4; r++) {
      int vl = lhi * 4 + r;
      float hv = hbase[(size_t)(v0 + vl) * 64 + d];
      hval[nf][r] = hv;
      int byte = (vl * 128 + d * 2) ^ ((vl & 7) << 4);
      *(unsigned short*)(apre_l + byte) = f2bf(aacc[nf][r]);
      *(unsigned short*)(mpre_l + byte) = f2bf(macc[nf][r] * hv);
    }
  }
  f32x4 oa[4], om[4];
#pragma unroll
  for (int nf = 0; nf < 4; nf++) {
    oa[nf] = (f32x4){0.f, 0.f, 0.f, 0.f};
    om[nf] = (f32x4){0.f, 0.f, 0.f, 0.f};
  }
  int sw = (lr & 7) << 4;
#pragma unroll
  for (int kb = 0; kb < 64; kb += 32) {
    int off0 = lr * 128 + kb * 2 + lhi * 16;
    short8 pa = *(const short8*)(apre_l + (off0 ^ sw));
    short8 pm = *(const short8*)(mpre_l + (off0 ^ sw));
#pragma unroll
    for (int nf = 0; nf < 4; nf++) {
      const unsigned short* wa = W_addbf + (size_t)(nf * 16 + lr) * 64 + kb + lhi * 8;
      const unsigned short* wm = W_modbf + (size_t)(nf * 16 + lr) * 64 + kb + lhi * 8;
      short8 wav = *(const short8*)wa;
      short8 wmv = *(const short8*)wm;
      oa[nf] = __builtin_amdgcn_mfma_f32_16x16x32_bf16(pa, wav, oa[nf], 0, 0, 0);
      om[nf] = __builtin_amdgcn_mfma_f32_16x16x32_bf16(pm, wmv, om[nf], 0, 0, 0);
    }
  }
  float bb1 = beta1p[0], bb2 = beta2p[0], bb3 = beta3p[0];
  float* obase = out + (size_t)bt * 8192 + (size_t)v0 * 64;
#pragma unroll
  for (int nf = 0; nf < 4; nf++) {
    int d = nf * 16 + lr;
    float ba = b_add[d], bm = b_mod[d];
#pragma unroll
    for (int r = 0; r < 4; r++) {
      int vl = lhi * 4 + r;
      obase[(size_t)vl * 64 + d] =
          bb1 * hval[nf][r] + bb2 * (oa[nf][r] + ba) + bb3 * (om[nf][r] + bm);
    }
  }
}

// ---------------------------------------------------------------------------
extern "C" void kernel_launch(void* const* d_in, const int* in_sizes, int n_in,
                              void* d_out, int out_size, void* d_ws, size_t ws_size,
                              hipStream_t stream) {
  const float* h     = (const float*)d_in[0];
  const float* W1    = (const float*)d_in[1];
  const float* b1    = (const float*)d_in[2];
  const float* W2    = (const float*)d_in[3];
  const float* b2    = (const float*)d_in[4];
  const float* W3    = (const float*)d_in[5];
  const float* b3    = (const float*)d_in[6];
  const float* W4    = (const float*)d_in[7];
  const float* b4    = (const float*)d_in[8];
  const float* A_a   = (const float*)d_in[9];
  const float* A_m   = (const float*)d_in[10];
  const float* W_add = (const float*)d_in[11];
  const float* b_add = (const float*)d_in[12];
  const float* W_mod = (const float*)d_in[13];
  const float* b_mod = (const float*)d_in[14];
  const float* beta1 = (const float*)d_in[15];
  const float* beta2 = (const float*)d_in[16];
  const float* beta3 = (const float*)d_in[17];
  float* out = (float*)d_out;

  char* ws = (char*)d_ws;
  float* fuv             = (float*)(ws);                         // 512 KB
  unsigned short* wTbf   = (unsigned short*)(ws + 512 * 1024);   // 128 KB
  unsigned short* A_mTbf = (unsigned short*)(ws + 640 * 1024);   // 32 KB
  unsigned short* W_addbf= (unsigned short*)(ws + 672 * 1024);   // 8 KB
  unsigned short* W_modbf= (unsigned short*)(ws + 680 * 1024);   // 8 KB
  unsigned short* W2bf   = (unsigned short*)(ws + 688 * 1024);   // 64 KB
  unsigned short* W3bf   = (unsigned short*)(ws + 752 * 1024);   // 32 KB
  unsigned short* W1bf   = (unsigned short*)(ws + 784 * 1024);   // 640 KB
  unsigned short* hbf    = (unsigned short*)(ws + 1424 * 1024);  // 1280 KB
  unsigned short* hbfT   = (unsigned short*)(ws + 2704 * 1024);  // 1280 KB

  k_conv_a<<<240, 256, 0, stream>>>(h, W1, hbf, W1bf);
  k_fuv2<<<372, 128, 0, stream>>>(hbf, W1bf, h, W2, W3, A_m, W_add, W_mod,
                                  fuv, W2bf, W3bf, A_mTbf, W_addbf, W_modbf,
                                  hbfT);
  k_pair<<<512, 256, 0, stream>>>(fuv, b1, W2bf, b2, W3bf, b3, W4, b4, A_a, wTbf);
  k_out_mfma<<<640, 64, 0, stream>>>(h, wTbf, A_mTbf, hbfT, W_addbf, W_modbf,
                                     b_add, b_mod, beta1, beta2, beta3, out);
}